// Round 11
// baseline (472.024 us; speedup 1.0000x reference)
//
#include <hip/hip_runtime.h>
#include <hip/hip_bf16.h>

typedef __hip_bfloat16 bf16;
typedef __attribute__((ext_vector_type(8))) short bf16x8;   // 8 bf16 (4 VGPRs)
typedef __attribute__((ext_vector_type(4))) float f32x4;    // MFMA accum

__device__ __forceinline__ float b2f(bf16 v) { return __bfloat162float(v); }
__device__ __forceinline__ bf16 f2b(float v) { return __float2bfloat16(v); }

// Scalar load/store from an external buffer whose dtype is decided by isb.
__device__ __forceinline__ float ldx(const void* p, size_t i, bool isb) {
    return isb ? b2f(((const bf16*)p)[i]) : ((const float*)p)[i];
}
__device__ __forceinline__ void stx(void* p, size_t i, bool isb, float v) {
    if (isb) ((bf16*)p)[i] = f2b(v);
    else     ((float*)p)[i] = v;
}
// Vector (8-elem) external load; i must be a multiple of 8.
__device__ __forceinline__ void ldx8(const void* p, size_t i, bool isb, float* o) {
    if (isb) {
        const bf16x8 v = *(const bf16x8*)((const bf16*)p + i);
#pragma unroll
        for (int j = 0; j < 8; j++) o[j] = b2f(((const bf16*)&v)[j]);
    } else {
        const float4 v0 = *(const float4*)((const float*)p + i);
        const float4 v1 = *(const float4*)((const float*)p + i + 4);
        o[0]=v0.x; o[1]=v0.y; o[2]=v0.z; o[3]=v0.w;
        o[4]=v1.x; o[5]=v1.y; o[6]=v1.z; o[7]=v1.w;
    }
}

// ---------------------------------------------------------------------------
// Dtype sniffer (verified round 3): decides fp32 vs bf16 external data.
// ---------------------------------------------------------------------------
__global__ void sniff_kernel(const void* __restrict__ x, int* __restrict__ flag) {
    const unsigned* w = (const unsigned*)x;
    const int t = threadIdx.x;
    int cnt = 0;
#pragma unroll
    for (int i = 0; i < 4; i++) {
        const unsigned word = w[t * 4 + i];
        const int e = (word >> 23) & 0xFF;
        cnt += (e >= 192) ? 1 : 0;
    }
    __shared__ int red[4];
#pragma unroll
    for (int o = 32; o > 0; o >>= 1) cnt += __shfl_down(cnt, o);
    if ((t & 63) == 0) red[t >> 6] = cnt;
    __syncthreads();
    if (t == 0) flag[0] = ((red[0] + red[1] + red[2] + red[3]) >= 512) ? 1 : 0;
}

// ---------------------------------------------------------------------------
// Merged weight convert+transpose for BOTH attention phases in one dispatch:
// grid (16,16,8): z 0..3 = SA {wq, wkv-lo, wkv-hi, wo} -> WT*, z 4..7 = CA
// -> WT2*. 64x64 LDS-tiled transpose, K=1024 for all.
// ---------------------------------------------------------------------------
__global__ void wconv8_kernel(const void* __restrict__ Wq,
                              const void* __restrict__ Wkv,
                              const void* __restrict__ Wo,
                              const void* __restrict__ Wq2,
                              const void* __restrict__ Wkv2,
                              const void* __restrict__ Wo2,
                              bf16* __restrict__ WTq, bf16* __restrict__ WTkv,
                              bf16* __restrict__ WTo,
                              bf16* __restrict__ WTq2, bf16* __restrict__ WTkv2,
                              bf16* __restrict__ WTo2,
                              const int* __restrict__ flagp) {
    const bool isb = (*flagp != 0);
    const int z = blockIdx.z;
    const int zz = z & 3;
    const bool ca = z >= 4;
    const void* W = ca ? ((zz == 0) ? Wq2 : (zz == 3) ? Wo2 : Wkv2)
                       : ((zz == 0) ? Wq  : (zz == 3) ? Wo  : Wkv);
    bf16* Wt      = ca ? ((zz == 0) ? WTq2 : (zz == 3) ? WTo2 : WTkv2)
                       : ((zz == 0) ? WTq  : (zz == 3) ? WTo  : WTkv);
    const int N   = (zz == 1 || zz == 2) ? 2048 : 1024;
    const int K = 1024;
    __shared__ float T[64][65];
    const int n0 = blockIdx.x * 64 + ((zz == 2) ? 1024 : 0);
    const int k0 = blockIdx.y * 64;
    const int t = threadIdx.x;
    const int rr = t >> 3, c8 = (t & 7) * 8;
#pragma unroll
    for (int i = 0; i < 2; i++) {
        const int row = rr + i * 32;
        float v[8];
        ldx8(W, (size_t)(k0 + row) * N + n0 + c8, isb, v);
#pragma unroll
        for (int j = 0; j < 8; j++) T[row][c8 + j] = v[j];
    }
    __syncthreads();
#pragma unroll
    for (int i = 0; i < 2; i++) {
        const int row = rr + i * 32;   // n-index within tile
        bf16x8 ov;
#pragma unroll
        for (int j = 0; j < 8; j++) ((bf16*)&ov)[j] = f2b(T[c8 + j][row]);
        *(bf16x8*)(Wt + (size_t)(n0 + row) * K + k0 + c8) = ov;
    }
}

// ---------------------------------------------------------------------------
// LayerNorm over F=1024, batch-fused via grid.z (per-batch strides in elems).
// ---------------------------------------------------------------------------
__global__ void ln_dual_kernel(const void* __restrict__ in, size_t in_off, long in_bs,
                               int in_ext,
                               const void* __restrict__ g1, const void* __restrict__ b1,
                               const void* __restrict__ g2, const void* __restrict__ b2,
                               bf16* __restrict__ out1, bf16* __restrict__ out2,
                               long out_bs, const int* __restrict__ flagp) {
    const int F = 1024;
    const bool isb = (*flagp != 0);
    const bool inb = in_ext ? isb : true;
    const int row = blockIdx.x;
    const int z = blockIdx.z;
    const int t = threadIdx.x;
    const size_t base = in_off + (size_t)z * in_bs + (size_t)row * F;
    const size_t obase = (size_t)z * out_bs + (size_t)row * F;

    float v[4];
    float s = 0.f;
#pragma unroll
    for (int i = 0; i < 4; i++) { v[i] = ldx(in, base + t + 256 * i, inb); s += v[i]; }

    __shared__ float red1[4];
    __shared__ float red2[4];
#pragma unroll
    for (int o = 32; o > 0; o >>= 1) s += __shfl_down(s, o);
    if ((t & 63) == 0) red1[t >> 6] = s;
    __syncthreads();
    const float mean = (red1[0] + red1[1] + red1[2] + red1[3]) * (1.0f / F);

    float ss = 0.f;
#pragma unroll
    for (int i = 0; i < 4; i++) { float d = v[i] - mean; ss += d * d; }
#pragma unroll
    for (int o = 32; o > 0; o >>= 1) ss += __shfl_down(ss, o);
    if ((t & 63) == 0) red2[t >> 6] = ss;
    __syncthreads();
    const float var = (red2[0] + red2[1] + red2[2] + red2[3]) * (1.0f / F);
    const float rn = rsqrtf(var + 1e-5f);

#pragma unroll
    for (int i = 0; i < 4; i++) {
        const int idx = t + 256 * i;
        const float nv = (v[i] - mean) * rn;
        out1[obase + idx] = f2b(nv * ldx(g1, idx, isb) + ldx(b1, idx, isb));
        if (out2) out2[obase + idx] = f2b(nv * ldx(g2, idx, isb) + ldx(b2, idx, isb));
    }
}

// ---------------------------------------------------------------------------
// Grouped GEMM args.
// ---------------------------------------------------------------------------
struct GArgs {
    const bf16* A; const bf16* Bt; void* C;
    const void* bias; const void* res;
    bf16* kb0; bf16* kb1;
    int c_ext, res_ext, N, mode, zsplit, zrows, nbx, nby;
};

// ---------------------------------------------------------------------------
// ROUND 11: grouped 64x64-tile GEMM for the BIG 3-slot dispatch. Round 10
// proved the occupancy lever (64^2, 4 blocks/CU) on the small GEMMs; the
// big dispatch at 128^2 runs 896 blocks = 3.5 blocks/CU (14 waves/CU) at an
// estimated ~200-250 TF. 64^2 tiles -> 3584 blocks, LDS 18.4 KB caps ~6-8
// blocks/CU = 24-32 waves/CU. MFMA core = verified gemm_t64/gemm_mfma
// fragment pattern. Mode-1 epilogues re-derived for 64-col blocks: K block
// keeps the verified row-major store; V block does a single-pass LDS
// transpose (T[64][72] reusing As) then 16B-contiguous V^T stores (round-8
// coalescing win preserved).
// ---------------------------------------------------------------------------
__global__ __launch_bounds__(256) void gemm_t64g(GArgs ga, GArgs gb, GArgs gc,
                                                 const int* __restrict__ flagp) {
    int bx = (int)blockIdx.x;
    GArgs g;
    if (bx < ga.nbx) { g = ga; }
    else if (bx < ga.nbx + gb.nbx) { g = gb; bx -= ga.nbx; }
    else { g = gc; bx -= ga.nbx + gb.nbx; }
    const int by = (int)blockIdx.y;
    if (by >= g.nby) return;               // block-uniform: no divergent barrier

    const int K = 1024;
    const bool isb = (*flagp != 0);

    __shared__ bf16 As[64][72];
    __shared__ bf16 Bs[64][72];

    const int t = threadIdx.x;
    const int w = t >> 6, lane = t & 63, li = lane & 15, quad = lane >> 4;
    const int wm = (w & 1) * 32, wn = (w >> 1) * 32;
    const int bm = by * 64, bn = bx * 64;

    f32x4 acc[2][2];
#pragma unroll
    for (int mi = 0; mi < 2; mi++)
#pragma unroll
        for (int ni = 0; ni < 2; ni++)
#pragma unroll
            for (int r = 0; r < 4; r++) acc[mi][ni][r] = 0.f;

    for (int k0 = 0; k0 < K; k0 += 64) {
#pragma unroll
        for (int c = 0; c < 2; c++) {
            const int d = c * 256 + t;
            const int row = d >> 3, ch = (d & 7) * 8;
            *(bf16x8*)&As[row][ch] = *(const bf16x8*)(g.A + (size_t)(bm + row) * K + k0 + ch);
            *(bf16x8*)&Bs[row][ch] = *(const bf16x8*)(g.Bt + (size_t)(bn + row) * K + k0 + ch);
        }
        __syncthreads();
#pragma unroll
        for (int kc = 0; kc < 2; kc++) {
            bf16x8 af[2], bfr[2];
#pragma unroll
            for (int mi = 0; mi < 2; mi++)
                af[mi] = *(const bf16x8*)&As[wm + mi * 16 + li][kc * 32 + quad * 8];
#pragma unroll
            for (int ni = 0; ni < 2; ni++)
                bfr[ni] = *(const bf16x8*)&Bs[wn + ni * 16 + li][kc * 32 + quad * 8];
#pragma unroll
            for (int mi = 0; mi < 2; mi++)
#pragma unroll
                for (int ni = 0; ni < 2; ni++)
                    acc[mi][ni] = __builtin_amdgcn_mfma_f32_16x16x32_bf16(
                        af[mi], bfr[ni], acc[mi][ni], 0, 0, 0);
        }
        __syncthreads();
    }

    if (g.mode == 1) {
        if (bn >= 1024) {
            // ---- V block: single-pass LDS transpose + coalesced V^T ----
            const int batch = (bm < g.zsplit) ? 0 : 1;   // 64 | zsplit
            bf16* kb = batch ? g.kb1 : g.kb0;
            const int brow = bm - batch * g.zsplit;
            const int vc0 = bn - 1024;
            bf16 (*T)[72] = (bf16(*)[72])&As[0][0];      // 64x72 = As exactly
#pragma unroll
            for (int mi = 0; mi < 2; mi++)
#pragma unroll
                for (int ni = 0; ni < 2; ni++)
#pragma unroll
                    for (int r = 0; r < 4; r++)
                        T[wn + ni * 16 + li][wm + mi * 16 + quad * 4 + r] =
                            f2b(acc[mi][ni][r]);
            __syncthreads();
            const int c = t >> 2, seg = t & 3;           // c: V^T row, seg: 32B
            bf16* dst = kb + (size_t)1024 * g.zrows
                        + (size_t)(vc0 + c) * g.zrows + brow + seg * 16;
            *(bf16x8*)dst       = *(const bf16x8*)&T[c][seg * 16];
            *(bf16x8*)(dst + 8) = *(const bf16x8*)&T[c][seg * 16 + 8];
            return;
        }
        // ---- K block: verified coalesced row-major store ----
#pragma unroll
        for (int mi = 0; mi < 2; mi++)
#pragma unroll
            for (int r = 0; r < 4; r++) {
                const int row = bm + wm + mi * 16 + quad * 4 + r;
                bf16* kb = (row < g.zsplit) ? g.kb0 : g.kb1;
                const int lrow = (row < g.zsplit) ? row : row - g.zsplit;
#pragma unroll
                for (int ni = 0; ni < 2; ni++) {
                    const int col = bn + wn + ni * 16 + li;
                    kb[(size_t)lrow * 1024 + col] = f2b(acc[mi][ni][r]);
                }
            }
        return;
    }

#pragma unroll
    for (int mi = 0; mi < 2; mi++)
#pragma unroll
        for (int r = 0; r < 4; r++) {
            const int row = bm + wm + mi * 16 + quad * 4 + r;
#pragma unroll
            for (int ni = 0; ni < 2; ni++) {
                const int col = bn + wn + ni * 16 + li;
                float v = acc[mi][ni][r];
                if (g.bias) v += ldx(g.bias, col, isb);
                if (g.res)  v += ldx(g.res, (size_t)row * g.N + col, g.res_ext ? isb : true);
                stx(g.C, (size_t)row * g.N + col, g.c_ext ? isb : true, v);
            }
        }
}

// ---------------------------------------------------------------------------
// Round-10 verified: 64x64-tile mode-0 GEMM for the three standalone GEMMs
// (SA-oproj, CA-q, CA-oproj), grid (16,64) = 4 blocks/CU. WIN: −21.6 µs.
// ---------------------------------------------------------------------------
__global__ __launch_bounds__(256) void gemm_t64(
    const bf16* __restrict__ A, const bf16* __restrict__ Bt,
    void* __restrict__ C, int c_ext,
    const void* __restrict__ bias,
    const void* __restrict__ res, int res_ext, int N,
    const int* __restrict__ flagp) {

    const int K = 1024;
    const bool isb = (*flagp != 0);

    __shared__ bf16 As[64][72];
    __shared__ bf16 Bs[64][72];

    const int t = threadIdx.x;
    const int w = t >> 6, lane = t & 63, li = lane & 15, quad = lane >> 4;
    const int wm = (w & 1) * 32, wn = (w >> 1) * 32;
    const int bm = blockIdx.y * 64, bn = blockIdx.x * 64;

    f32x4 acc[2][2];
#pragma unroll
    for (int mi = 0; mi < 2; mi++)
#pragma unroll
        for (int ni = 0; ni < 2; ni++)
#pragma unroll
            for (int r = 0; r < 4; r++) acc[mi][ni][r] = 0.f;

    for (int k0 = 0; k0 < K; k0 += 64) {
#pragma unroll
        for (int c = 0; c < 2; c++) {
            const int d = c * 256 + t;
            const int row = d >> 3, ch = (d & 7) * 8;
            *(bf16x8*)&As[row][ch] = *(const bf16x8*)(A + (size_t)(bm + row) * K + k0 + ch);
            *(bf16x8*)&Bs[row][ch] = *(const bf16x8*)(Bt + (size_t)(bn + row) * K + k0 + ch);
        }
        __syncthreads();
#pragma unroll
        for (int kc = 0; kc < 2; kc++) {
            bf16x8 af[2], bfr[2];
#pragma unroll
            for (int mi = 0; mi < 2; mi++)
                af[mi] = *(const bf16x8*)&As[wm + mi * 16 + li][kc * 32 + quad * 8];
#pragma unroll
            for (int ni = 0; ni < 2; ni++)
                bfr[ni] = *(const bf16x8*)&Bs[wn + ni * 16 + li][kc * 32 + quad * 8];
#pragma unroll
            for (int mi = 0; mi < 2; mi++)
#pragma unroll
                for (int ni = 0; ni < 2; ni++)
                    acc[mi][ni] = __builtin_amdgcn_mfma_f32_16x16x32_bf16(
                        af[mi], bfr[ni], acc[mi][ni], 0, 0, 0);
        }
        __syncthreads();
    }

#pragma unroll
    for (int mi = 0; mi < 2; mi++)
#pragma unroll
        for (int r = 0; r < 4; r++) {
            const int row = bm + wm + mi * 16 + quad * 4 + r;
#pragma unroll
            for (int ni = 0; ni < 2; ni++) {
                const int col = bn + wn + ni * 16 + li;
                float v = acc[mi][ni][r];
                if (bias) v += ldx(bias, col, isb);
                if (res)  v += ldx(res, (size_t)row * N + col, res_ext ? isb : true);
                stx(C, (size_t)row * N + col, c_ext ? isb : true, v);
            }
        }
}

// ---------------------------------------------------------------------------
// Slow-path MFMA GEMM (round-7 verified, used only if workspace is small).
// ---------------------------------------------------------------------------
__global__ __launch_bounds__(256) void gemm_mfma(
    const bf16* __restrict__ A, long a_bs, const void* __restrict__ W,
    void* __restrict__ C, size_t c_off, long c_bs, int c_ext,
    const void* __restrict__ bias,
    const void* __restrict__ res, size_t res_off, long res_bs, int res_ext,
    int K, int N, int mode, int R,
    bf16* __restrict__ kb0, bf16* __restrict__ kb1,
    const int* __restrict__ flagp) {

    const bool isb = (*flagp != 0);
    const bool resb = res_ext ? isb : true;
    const bool cb = c_ext ? isb : true;
    const int z = blockIdx.z;

    const bf16* Az = A + (size_t)z * a_bs;
    const size_t coz = c_off + (size_t)z * c_bs;
    const size_t roz = res_off + (size_t)z * res_bs;

    __shared__ bf16 As[64][72];
    __shared__ bf16 Bs[64][72];

    const int t = threadIdx.x;
    const int w = t >> 6, lane = t & 63, li = lane & 15, quad = lane >> 4;
    const int wm = (w & 1) * 32, wn = (w >> 1) * 32;
    const int bm = blockIdx.y * 64, bn = blockIdx.x * 64;

    f32x4 acc[2][2];
#pragma unroll
    for (int mi = 0; mi < 2; mi++)
#pragma unroll
        for (int ni = 0; ni < 2; ni++)
#pragma unroll
            for (int r = 0; r < 4; r++) acc[mi][ni][r] = 0.f;

    for (int k0 = 0; k0 < K; k0 += 64) {
#pragma unroll
        for (int c = 0; c < 2; c++) {
            const int lin = t * 16 + c * 8;
            const int row = lin >> 6, kk = lin & 63;
            *(bf16x8*)&As[row][kk] = *(const bf16x8*)(Az + (size_t)(bm + row) * K + k0 + kk);
        }
#pragma unroll
        for (int c = 0; c < 2; c++) {
            const int lin = t * 16 + c * 8;
            const int kk = lin >> 6, n0 = lin & 63;
            float v[8];
            ldx8(W, (size_t)(k0 + kk) * N + bn + n0, isb, v);
            const int st = t & 7;
#pragma unroll
            for (int i = 0; i < 8; i++) {
                const int ii = (i + st) & 7;
                Bs[n0 + ii][kk] = f2b(v[ii]);
            }
        }
        __syncthreads();
#pragma unroll
        for (int kc = 0; kc < 2; kc++) {
            bf16x8 af[2], bfr[2];
#pragma unroll
            for (int mi = 0; mi < 2; mi++)
                af[mi] = *(const bf16x8*)&As[wm + mi * 16 + li][kc * 32 + quad * 8];
#pragma unroll
            for (int ni = 0; ni < 2; ni++)
                bfr[ni] = *(const bf16x8*)&Bs[wn + ni * 16 + li][kc * 32 + quad * 8];
#pragma unroll
            for (int mi = 0; mi < 2; mi++)
#pragma unroll
                for (int ni = 0; ni < 2; ni++)
                    acc[mi][ni] = __builtin_amdgcn_mfma_f32_16x16x32_bf16(
                        af[mi], bfr[ni], acc[mi][ni], 0, 0, 0);
        }
        __syncthreads();
    }

    if (mode == 1) {
        bf16* kb = z ? kb1 : kb0;
#pragma unroll
        for (int mi = 0; mi < 2; mi++)
#pragma unroll
            for (int r = 0; r < 4; r++) {
                const int row = bm + wm + mi * 16 + quad * 4 + r;
#pragma unroll
                for (int ni = 0; ni < 2; ni++) {
                    const int col = bn + wn + ni * 16 + li;
                    const float v = acc[mi][ni][r];
                    if (col < 1024)
                        kb[(size_t)row * 1024 + col] = f2b(v);
                    else
                        kb[(size_t)1024 * R + (size_t)(col - 1024) * R + row] = f2b(v);
                }
            }
        return;
    }

#pragma unroll
    for (int mi = 0; mi < 2; mi++)
#pragma unroll
        for (int r = 0; r < 4; r++) {
            const int row = bm + wm + mi * 16 + quad * 4 + r;
#pragma unroll
            for (int ni = 0; ni < 2; ni++) {
                const int col = bn + wn + ni * 16 + li;
                float v = acc[mi][ni][r];
                if (bias) v += ldx(bias, col, isb);
                if (res)  v += ldx(res, roz + (size_t)row * N + col, resb);
                stx(C, coz + (size_t)row * N + col, cb, v);
            }
        }
}

// ---------------------------------------------------------------------------
// attn_flash: round-0 verified body — best measured (134.6 µs SA). Five
// variants failed; frozen. (Codegen lottery across builds: ±5 µs.)
// ---------------------------------------------------------------------------
__global__ __launch_bounds__(64) void attn_flash(
    const bf16* __restrict__ qb, const bf16* __restrict__ kv0,
    const bf16* __restrict__ kv1,
    const void* __restrict__ rel_emb, bf16* __restrict__ out,
    long qo_bs, long out_bs, int m, int rel_off, const int* __restrict__ flagp) {

    const float SC = 0.125f * 1.44269504f;
    const bool isb = (*flagp != 0);
    const int id = blockIdx.x;
    const int xcd = id & 7;
    const int slot = id >> 3;
    const int c = (slot >> 6) * 8 + xcd;
    const int h = c & 15, z = c >> 4;
    const int q0 = (slot & 63) * 32;
    const int t = threadIdx.x;
    const int li = t & 15, quad = t >> 4;

    const bf16* qz = qb + (size_t)z * qo_bs;
    bf16* oz = out + (size_t)z * out_bs;
    const bf16* kb = z ? kv1 : kv0;
    const bf16* vtb = kb + (size_t)m * 1024;

    __shared__ float bias_s[32];
    __shared__ float tab[2080];
    __shared__ bf16 Ps[16][40];

    if (t < 32) bias_s[t] = ldx(rel_emb, t * 16 + h, isb) * SC - 40.0f;
    __syncthreads();

    const int tsz = m + 31;
    for (int i = t; i < tsz; i += 64) {
        const int rel = i - 31 - q0 + rel_off;
        const int ab = rel < 0 ? -rel : rel;
        int bucket = rel >= 0 ? 16 : 0;
        if (ab < 8) {
            bucket += ab;
        } else {
            const int p = 31 - __clz(ab);
            const int k2 = 2 * p + ((ab * ab >= (1 << (2 * p + 1))) ? 1 : 0);
            const int val = k2 + 2;
            bucket += (val > 15) ? 15 : val;
        }
        tab[i] = bias_s[bucket];
    }
    __syncthreads();

    bf16x8 aq[2][2];
#pragma unroll
    for (int g = 0; g < 2; g++)
#pragma unroll
        for (int kc = 0; kc < 2; kc++)
            aq[g][kc] = *(const bf16x8*)(qz + (size_t)(q0 + g * 16 + li) * 1024
                                         + h * 64 + kc * 32 + quad * 8);

    bf16x8 ones;
#pragma unroll
    for (int j = 0; j < 8; j++) ((short*)&ones)[j] = 0x3F80;

    f32x4 o[2][4], lac[2];
#pragma unroll
    for (int g = 0; g < 2; g++) {
#pragma unroll
        for (int r = 0; r < 4; r++) lac[g][r] = 0.f;
#pragma unroll
        for (int nb = 0; nb < 4; nb++)
#pragma unroll
            for (int r = 0; r < 4; r++) o[g][nb][r] = 0.f;
    }

    for (int j0 = 0; j0 < m; j0 += 32) {
        bf16x8 kf[4], vf[4];
#pragma unroll
        for (int nb = 0; nb < 2; nb++)
#pragma unroll
            for (int kc = 0; kc < 2; kc++)
                kf[nb * 2 + kc] = *(const bf16x8*)(
                    kb + (size_t)(j0 + nb * 16 + li) * 1024 + h * 64 + kc * 32 + quad * 8);
#pragma unroll
        for (int nb = 0; nb < 4; nb++)
            vf[nb] = *(const bf16x8*)(
                vtb + (size_t)(h * 64 + nb * 16 + li) * m + j0 + quad * 8);

#pragma unroll
        for (int g = 0; g < 2; g++) {
            f32x4 s[2];
            __builtin_amdgcn_s_setprio(1);
#pragma unroll
            for (int nb = 0; nb < 2; nb++) {
                f32x4 a;
#pragma unroll
                for (int r = 0; r < 4; r++) a[r] = 0.f;
#pragma unroll
                for (int kc = 0; kc < 2; kc++)
                    a = __builtin_amdgcn_mfma_f32_16x16x32_bf16(aq[g][kc], kf[nb * 2 + kc],
                                                                a, 0, 0, 0);
                s[nb] = a;
            }
            __builtin_amdgcn_s_setprio(0);
#pragma unroll
            for (int nb = 0; nb < 2; nb++)
#pragma unroll
                for (int r = 0; r < 4; r++) {
                    const int ti = j0 + nb * 16 + li + 31 - (g * 16 + quad * 4 + r);
                    s[nb][r] = exp2f(fmaf(s[nb][r], SC, tab[ti]));
                }
#pragma unroll
            for (int nb = 0; nb < 2; nb++)
#pragma unroll
                for (int r = 0; r < 4; r++)
                    Ps[quad * 4 + r][nb * 16 + li] = f2b(s[nb][r]);
            const bf16x8 ap = *(const bf16x8*)&Ps[li][quad * 8];
            __builtin_amdgcn_s_setprio(1);
#pragma unroll
            for (int nb = 0; nb < 4; nb++)
                o[g][nb] = __builtin_amdgcn_mfma_f32_16x16x32_bf16(ap, vf[nb],
                                                                   o[g][nb], 0, 0, 0);
            lac[g] = __builtin_amdgcn_mfma_f32_16x16x32_bf16(ap, ones, lac[g], 0, 0, 0);
            __builtin_amdgcn_s_setprio(0);
        }
    }

#pragma unroll
    for (int g = 0; g < 2; g++)
#pragma unroll
        for (int r = 0; r < 4; r++) {
            const float inv = 1.0f / lac[g][r];
            const int qi = q0 + g * 16 + quad * 4 + r;
#pragma unroll
            for (int nb = 0; nb < 4; nb++)
                oz[(size_t)qi * 1024 + h * 64 + nb * 16 + li] = f2b(o[g][nb][r] * inv);
        }
}

// ---------------------------------------------------------------------------
// Launcher. Fast path (ws >= 56 MB + 256; measured ws = 256 MB):
//   F_A|F_B|F_C (24 MB) + WT (8) + F_X (8) + F_Y (6) + WT2 (8) = 54 MB.
// Round-10 schedule (best: 460.3 µs) with the BIG dispatch moved to 64x64
// tiles (gemm_t64g, ~6-8 blocks/CU). Fallback: round-7 plan (24 MB).
// ---------------------------------------------------------------------------
extern "C" void kernel_launch(void* const* d_in, const int* in_sizes, int n_in,
                              void* d_out, int out_size, void* d_ws, size_t ws_size,
                              hipStream_t stream) {
    const long M1 = 1024 * 1024;
    const long M2 = 2 * 1024 * 1024;
    const long M4 = 4 * 1024 * 1024;
    if (ws_size < 24u * 1024 * 1024 + 256) return;

    const void* x      = d_in[0];
    const void* ctx    = d_in[1];
    const void* sa_ng  = d_in[2];
    const void* sa_nb  = d_in[3];
    const void* sa_ncg = d_in[4];
    const void* sa_ncb = d_in[5];
    const void* sa_wq  = d_in[6];
    const void* sa_wkv = d_in[7];
    const void* sa_wo  = d_in[8];
    const void* sa_bo  = d_in[9];
    const void* sa_rel = d_in[10];
    const void* ca_ng  = d_in[11];
    const void* ca_nb  = d_in[12];
    const void* ca_ncg = d_in[13];
    const void* ca_ncb = d_in[14];
    const void* ca_wq  = d_in[15];
    const void* ca_wkv = d_in[16];
    const void* ca_wo  = d_in[17];
    const void* ca_bo  = d_in[18];
    const void* ca_rel = d_in[19];

    int* flag = (int*)d_ws;
    bf16* F_A = (bf16*)((char*)d_ws + 256);
    bf16* F_B = F_A + M4;
    bf16* F_C = F_B + M4;
    bf16* WT  = F_C + M4;                // fast path only (SA weights)
    bf16* F_X = WT + M4;                 // fast path only (xn buffer)
    bf16* F_Y = F_X + M4;                // fast path only (ctx-LN + CA K/V)
    bf16* WT2 = F_Y + 3 * M1;            // fast path only (CA weights)
    bf16* qd  = (bf16*)d_out;            // d_out as bf16 scratch (q / ao)

    sniff_kernel<<<1, 256, 0, stream>>>(x, flag);

    if (ws_size >= 56u * 1024 * 1024 + 256) {
        bf16* WTq  = WT;                 // [1024][1024]
        bf16* WTkv = WT + M1;            // [2048][1024]
        bf16* WTo  = WT + 3 * M1;        // [1024][1024]
        bf16* WT2q  = WT2;
        bf16* WT2kv = WT2 + M1;
        bf16* WT2o  = WT2 + 3 * M1;
        bf16* CAK0 = F_Y + M1;           // z0: K[512][1024] + V^T[1024][512]
        bf16* CAK1 = F_Y + 2 * M1;       // z1: same layout

        // ===== prologue: all weight transposes + both input LNs =====
        wconv8_kernel<<<dim3(16, 16, 8), 256, 0, stream>>>(
            sa_wq, sa_wkv, sa_wo, ca_wq, ca_wkv, ca_wo,
            WTq, WTkv, WTo, WT2q, WT2kv, WT2o, flag);
        ln_dual_kernel<<<dim3(2048, 1, 2), 256, 0, stream>>>(
            x, 0, M2, 1, sa_ng, sa_nb, sa_ncg, sa_ncb, F_X, F_B, M2, flag);
        ln_dual_kernel<<<dim3(512, 1, 2), 256, 0, stream>>>(
            ctx, 0, 512 * 1024, 1, ca_ncg, ca_ncb, nullptr, nullptr,
            F_Y, nullptr, 512 * 1024, flag);

        // ===== BIG (64x64 tiles): SA-q + SA-kv + CA-kv =====
        {
            GArgs gq = {};
            gq.A = F_X; gq.Bt = WTq; gq.C = qd;
            gq.N = 1024; gq.nbx = 16; gq.nby = 64;
            GArgs gkv = {};
            gkv.A = F_B; gkv.Bt = WTkv;
            gkv.N = 2048; gkv.mode = 1; gkv.zsplit = 2048; gkv.zrows = 2048;
            gkv.kb0 = F_A; gkv.kb1 = F_C; gkv.nbx = 32; gkv.nby = 64;
            GArgs gca = {};
            gca.A = F_Y; gca.Bt = WT2kv;
            gca.N = 2048; gca.mode = 1; gca.zsplit = 512; gca.zrows = 512;
            gca.kb0 = CAK0; gca.kb1 = CAK1; gca.nbx = 32; gca.nby = 16;
            gemm_t64g<<<dim3(80, 64), 256, 0, stream>>>(gq, gkv, gca, flag);
        }

        // ===== self-attention + o-proj =====
        attn_flash<<<dim3(2048), 64, 0, stream>>>(
            qd, F_A, F_C, sa_rel, qd, M2, M2, 2048, 0, flag);
        gemm_t64<<<dim3(16, 64), 256, 0, stream>>>(
            qd, WTo, F_B, 0, sa_bo, x, 1, 1024, flag);

        // ===== cross-attention =====
        ln_dual_kernel<<<dim3(2048, 1, 2), 256, 0, stream>>>(
            F_B, 0, M2, 0, ca_ng, ca_nb, nullptr, nullptr, F_X, nullptr, M2, flag);
        gemm_t64<<<dim3(16, 64), 256, 0, stream>>>(
            F_X, WT2q, qd, 0, nullptr, nullptr, 0, 1024, flag);
        attn_flash<<<dim3(2048), 64, 0, stream>>>(
            qd, CAK0, CAK1, ca_rel, F_C, M2, M2, 512, 1536, flag);
        gemm_t64<<<dim3(16, 64), 256, 0, stream>>>(
            F_C, WT2o, d_out, 1, ca_bo, F_B, 0, 1024, flag);
        return;
    }

    // ================= fallback: round-7 verified plan =================
    ln_dual_kernel<<<dim3(2048, 1, 2), 256, 0, stream>>>(
        x, 0, M2, 1, sa_ng, sa_nb, sa_ncg, sa_ncb, F_A, F_B, M2, flag);
    gemm_mfma<<<dim3(16, 32, 2), 256, 0, stream>>>(
        F_A, M2, sa_wq, qd, 0, M2, 0, nullptr, nullptr, 0, 0, 0,
        1024, 1024, 0, 0, nullptr, nullptr, flag);
    gemm_mfma<<<dim3(32, 32, 2), 256, 0, stream>>>(
        F_B, M2, sa_wkv, nullptr, 0, 0, 0, nullptr, nullptr, 0, 0, 0,
        1024, 2048, 1, 2048, F_A, F_C, flag);
    attn_flash<<<dim3(2048), 64, 0, stream>>>(
        qd, F_A, F_C, sa_rel, qd, M2, M2, 2048, 0, flag);
    gemm_mfma<<<dim3(16, 32, 2), 256, 0, stream>>>(
        qd, M2, sa_wo, F_B, 0, M2, 0, sa_bo, x, 0, M2, 1,
        1024, 1024, 0, 0, nullptr, nullptr, flag);

    ln_dual_kernel<<<dim3(2048, 1, 2), 256, 0, stream>>>(
        F_B, 0, M2, 0, ca_ng, ca_nb, nullptr, nullptr, F_A, nullptr, M2, flag);
    ln_dual_kernel<<<dim3(512, 1, 2), 256, 0, stream>>>(
        ctx, 0, 512 * 1024, 1, ca_ncg, ca_ncb, nullptr, nullptr,
        F_C, nullptr, 512 * 1024, flag);
    gemm_mfma<<<dim3(16, 32, 2), 256, 0, stream>>>(
        F_A, M2, ca_wq, qd, 0, M2, 0, nullptr, nullptr, 0, 0, 0,
        1024, 1024, 0, 0, nullptr, nullptr, flag);
    gemm_mfma<<<dim3(32, 8, 2), 256, 0, stream>>>(
        F_C, 512 * 1024, ca_wkv, nullptr, 0, 0, 0, nullptr, nullptr, 0, 0, 0,
        1024, 2048, 1, 512, F_A, F_A + M1, flag);
    attn_flash<<<dim3(2048), 64, 0, stream>>>(
        qd, F_A, F_A + M1, ca_rel, F_C, M2, M2, 512, 1536, flag);
    gemm_mfma<<<dim3(16, 32, 2), 256, 0, stream>>>(
        F_C, M2, ca_wo, d_out, 0, M2, 1, ca_bo, F_B, 0, M2, 0,
        1024, 1024, 0, 0, nullptr, nullptr, flag);
}

// Round 12
// 459.090 us; speedup vs baseline: 1.0282x; 1.0282x over previous
//
#include <hip/hip_runtime.h>
#include <hip/hip_bf16.h>

typedef __hip_bfloat16 bf16;
typedef __attribute__((ext_vector_type(8))) short bf16x8;   // 8 bf16 (4 VGPRs)
typedef __attribute__((ext_vector_type(4))) float f32x4;    // MFMA accum

__device__ __forceinline__ float b2f(bf16 v) { return __bfloat162float(v); }
__device__ __forceinline__ bf16 f2b(float v) { return __float2bfloat16(v); }

// Scalar load/store from an external buffer whose dtype is decided by isb.
__device__ __forceinline__ float ldx(const void* p, size_t i, bool isb) {
    return isb ? b2f(((const bf16*)p)[i]) : ((const float*)p)[i];
}
__device__ __forceinline__ void stx(void* p, size_t i, bool isb, float v) {
    if (isb) ((bf16*)p)[i] = f2b(v);
    else     ((float*)p)[i] = v;
}
// Vector (8-elem) external load; i must be a multiple of 8.
__device__ __forceinline__ void ldx8(const void* p, size_t i, bool isb, float* o) {
    if (isb) {
        const bf16x8 v = *(const bf16x8*)((const bf16*)p + i);
#pragma unroll
        for (int j = 0; j < 8; j++) o[j] = b2f(((const bf16*)&v)[j]);
    } else {
        const float4 v0 = *(const float4*)((const float*)p + i);
        const float4 v1 = *(const float4*)((const float*)p + i + 4);
        o[0]=v0.x; o[1]=v0.y; o[2]=v0.z; o[3]=v0.w;
        o[4]=v1.x; o[5]=v1.y; o[6]=v1.z; o[7]=v1.w;
    }
}

// ---------------------------------------------------------------------------
// Dtype sniffer (verified round 3): decides fp32 vs bf16 external data.
// ---------------------------------------------------------------------------
__global__ void sniff_kernel(const void* __restrict__ x, int* __restrict__ flag) {
    const unsigned* w = (const unsigned*)x;
    const int t = threadIdx.x;
    int cnt = 0;
#pragma unroll
    for (int i = 0; i < 4; i++) {
        const unsigned word = w[t * 4 + i];
        const int e = (word >> 23) & 0xFF;
        cnt += (e >= 192) ? 1 : 0;
    }
    __shared__ int red[4];
#pragma unroll
    for (int o = 32; o > 0; o >>= 1) cnt += __shfl_down(cnt, o);
    if ((t & 63) == 0) red[t >> 6] = cnt;
    __syncthreads();
    if (t == 0) flag[0] = ((red[0] + red[1] + red[2] + red[3]) >= 512) ? 1 : 0;
}

// ---------------------------------------------------------------------------
// Merged weight convert+transpose for BOTH attention phases in one dispatch:
// grid (16,16,8): z 0..3 = SA {wq, wkv-lo, wkv-hi, wo} -> WT*, z 4..7 = CA
// -> WT2*. 64x64 LDS-tiled transpose, K=1024 for all.
// ---------------------------------------------------------------------------
__global__ void wconv8_kernel(const void* __restrict__ Wq,
                              const void* __restrict__ Wkv,
                              const void* __restrict__ Wo,
                              const void* __restrict__ Wq2,
                              const void* __restrict__ Wkv2,
                              const void* __restrict__ Wo2,
                              bf16* __restrict__ WTq, bf16* __restrict__ WTkv,
                              bf16* __restrict__ WTo,
                              bf16* __restrict__ WTq2, bf16* __restrict__ WTkv2,
                              bf16* __restrict__ WTo2,
                              const int* __restrict__ flagp) {
    const bool isb = (*flagp != 0);
    const int z = blockIdx.z;
    const int zz = z & 3;
    const bool ca = z >= 4;
    const void* W = ca ? ((zz == 0) ? Wq2 : (zz == 3) ? Wo2 : Wkv2)
                       : ((zz == 0) ? Wq  : (zz == 3) ? Wo  : Wkv);
    bf16* Wt      = ca ? ((zz == 0) ? WTq2 : (zz == 3) ? WTo2 : WTkv2)
                       : ((zz == 0) ? WTq  : (zz == 3) ? WTo  : WTkv);
    const int N   = (zz == 1 || zz == 2) ? 2048 : 1024;
    const int K = 1024;
    __shared__ float T[64][65];
    const int n0 = blockIdx.x * 64 + ((zz == 2) ? 1024 : 0);
    const int k0 = blockIdx.y * 64;
    const int t = threadIdx.x;
    const int rr = t >> 3, c8 = (t & 7) * 8;
#pragma unroll
    for (int i = 0; i < 2; i++) {
        const int row = rr + i * 32;
        float v[8];
        ldx8(W, (size_t)(k0 + row) * N + n0 + c8, isb, v);
#pragma unroll
        for (int j = 0; j < 8; j++) T[row][c8 + j] = v[j];
    }
    __syncthreads();
#pragma unroll
    for (int i = 0; i < 2; i++) {
        const int row = rr + i * 32;   // n-index within tile
        bf16x8 ov;
#pragma unroll
        for (int j = 0; j < 8; j++) ((bf16*)&ov)[j] = f2b(T[c8 + j][row]);
        *(bf16x8*)(Wt + (size_t)(n0 + row) * K + k0 + c8) = ov;
    }
}

// ---------------------------------------------------------------------------
// ROUND 12: merged prologue LayerNorm. Block-uniform split: blocks 0..2047
// normalize x rows (dual outputs: F_X with sa_n*, F_B with sa_nc*); blocks
// 2048..2559 normalize ctx rows (single output: F_Y with ca_nc*). Shared
// reduction body, divergence only at the final writes. Removes one dispatch
// and overlaps the short ctx-LN with the x-LN (grouping ledger: 3-for-3 +).
// ---------------------------------------------------------------------------
__global__ void ln_pro_kernel(const void* __restrict__ x, const void* __restrict__ ctx,
                              const void* __restrict__ g1, const void* __restrict__ b1,
                              const void* __restrict__ g2, const void* __restrict__ b2,
                              const void* __restrict__ g3, const void* __restrict__ b3,
                              bf16* __restrict__ outX, bf16* __restrict__ outB,
                              bf16* __restrict__ outY,
                              const int* __restrict__ flagp) {
    const int F = 1024;
    const bool isb = (*flagp != 0);
    const int bid = blockIdx.x;          // 0..2559
    const int z = blockIdx.z;
    const int t = threadIdx.x;
    const bool isCtx = bid >= 2048;
    const int row = isCtx ? bid - 2048 : bid;
    const void* in = isCtx ? ctx : x;
    const size_t base = (isCtx ? (size_t)z * (512 * 1024)
                               : (size_t)z * (2048 * 1024)) + (size_t)row * F;

    float v[4];
    float s = 0.f;
#pragma unroll
    for (int i = 0; i < 4; i++) { v[i] = ldx(in, base + t + 256 * i, isb); s += v[i]; }

    __shared__ float red1[4];
    __shared__ float red2[4];
#pragma unroll
    for (int o = 32; o > 0; o >>= 1) s += __shfl_down(s, o);
    if ((t & 63) == 0) red1[t >> 6] = s;
    __syncthreads();
    const float mean = (red1[0] + red1[1] + red1[2] + red1[3]) * (1.0f / F);

    float ss = 0.f;
#pragma unroll
    for (int i = 0; i < 4; i++) { float d = v[i] - mean; ss += d * d; }
#pragma unroll
    for (int o = 32; o > 0; o >>= 1) ss += __shfl_down(ss, o);
    if ((t & 63) == 0) red2[t >> 6] = ss;
    __syncthreads();
    const float var = (red2[0] + red2[1] + red2[2] + red2[3]) * (1.0f / F);
    const float rn = rsqrtf(var + 1e-5f);

    if (isCtx) {
        const size_t obase = (size_t)z * (512 * 1024) + (size_t)row * F;
#pragma unroll
        for (int i = 0; i < 4; i++) {
            const int idx = t + 256 * i;
            const float nv = (v[i] - mean) * rn;
            outY[obase + idx] = f2b(nv * ldx(g3, idx, isb) + ldx(b3, idx, isb));
        }
    } else {
        const size_t obase = (size_t)z * (2048 * 1024) + (size_t)row * F;
#pragma unroll
        for (int i = 0; i < 4; i++) {
            const int idx = t + 256 * i;
            const float nv = (v[i] - mean) * rn;
            outX[obase + idx] = f2b(nv * ldx(g1, idx, isb) + ldx(b1, idx, isb));
            outB[obase + idx] = f2b(nv * ldx(g2, idx, isb) + ldx(b2, idx, isb));
        }
    }
}

// ---------------------------------------------------------------------------
// LayerNorm over F=1024, batch-fused via grid.z (per-batch strides in elems).
// Used for the mid-pipeline CA-x LN.
// ---------------------------------------------------------------------------
__global__ void ln_dual_kernel(const void* __restrict__ in, size_t in_off, long in_bs,
                               int in_ext,
                               const void* __restrict__ g1, const void* __restrict__ b1,
                               const void* __restrict__ g2, const void* __restrict__ b2,
                               bf16* __restrict__ out1, bf16* __restrict__ out2,
                               long out_bs, const int* __restrict__ flagp) {
    const int F = 1024;
    const bool isb = (*flagp != 0);
    const bool inb = in_ext ? isb : true;
    const int row = blockIdx.x;
    const int z = blockIdx.z;
    const int t = threadIdx.x;
    const size_t base = in_off + (size_t)z * in_bs + (size_t)row * F;
    const size_t obase = (size_t)z * out_bs + (size_t)row * F;

    float v[4];
    float s = 0.f;
#pragma unroll
    for (int i = 0; i < 4; i++) { v[i] = ldx(in, base + t + 256 * i, inb); s += v[i]; }

    __shared__ float red1[4];
    __shared__ float red2[4];
#pragma unroll
    for (int o = 32; o > 0; o >>= 1) s += __shfl_down(s, o);
    if ((t & 63) == 0) red1[t >> 6] = s;
    __syncthreads();
    const float mean = (red1[0] + red1[1] + red1[2] + red1[3]) * (1.0f / F);

    float ss = 0.f;
#pragma unroll
    for (int i = 0; i < 4; i++) { float d = v[i] - mean; ss += d * d; }
#pragma unroll
    for (int o = 32; o > 0; o >>= 1) ss += __shfl_down(ss, o);
    if ((t & 63) == 0) red2[t >> 6] = ss;
    __syncthreads();
    const float var = (red2[0] + red2[1] + red2[2] + red2[3]) * (1.0f / F);
    const float rn = rsqrtf(var + 1e-5f);

#pragma unroll
    for (int i = 0; i < 4; i++) {
        const int idx = t + 256 * i;
        const float nv = (v[i] - mean) * rn;
        out1[obase + idx] = f2b(nv * ldx(g1, idx, isb) + ldx(b1, idx, isb));
        if (out2) out2[obase + idx] = f2b(nv * ldx(g2, idx, isb) + ldx(b2, idx, isb));
    }
}

// ---------------------------------------------------------------------------
// Grouped GEMM args. C = A[R,1024] @ Bt^T, 128x128 tile, BK=64, 4 waves.
// ---------------------------------------------------------------------------
struct GArgs {
    const bf16* A; const bf16* Bt; void* C;
    const void* bias; const void* res;
    bf16* kb0; bf16* kb1;
    int c_ext, res_ext, N, mode, zsplit, zrows, nbx, nby;
};

// ---------------------------------------------------------------------------
// Reg-staged grouped GEMM (verified body, padded LDS). Mode-1 V-half writes
// V^T via LDS transpose (round-8 win). Used for the BIG 3-slot dispatch at
// 128^2 tiles / 3.5 blocks/CU — round 11 proved 64^2 tiles REGRESS here
// (throughput regime: per-block MFMA:barrier ratio beats extra occupancy).
// ---------------------------------------------------------------------------
__global__ __launch_bounds__(256) void gemm_fused(GArgs ga, GArgs gb, GArgs gc,
                                                  const int* __restrict__ flagp) {
    int bx = (int)blockIdx.x;
    GArgs g;
    if (bx < ga.nbx) { g = ga; }
    else if (bx < ga.nbx + gb.nbx) { g = gb; bx -= ga.nbx; }
    else { g = gc; bx -= ga.nbx + gb.nbx; }
    const int by = (int)blockIdx.y;
    if (by >= g.nby) return;               // block-uniform: no divergent barrier

    const int K = 1024;
    const bool isb = (*flagp != 0);

    __shared__ bf16 As[128][72];
    __shared__ bf16 Bs[128][72];

    const int t = threadIdx.x;
    const int w = t >> 6, lane = t & 63, li = lane & 15, quad = lane >> 4;
    const int wm = (w & 1) * 64, wn = (w >> 1) * 64;
    const int bm = by * 128, bn = bx * 128;

    f32x4 acc[4][4];
#pragma unroll
    for (int mi = 0; mi < 4; mi++)
#pragma unroll
        for (int ni = 0; ni < 4; ni++)
#pragma unroll
            for (int r = 0; r < 4; r++) acc[mi][ni][r] = 0.f;

    for (int k0 = 0; k0 < K; k0 += 64) {
#pragma unroll
        for (int c = 0; c < 4; c++) {
            const int d = c * 256 + t;
            const int row = d >> 3, ch = (d & 7) * 8;
            *(bf16x8*)&As[row][ch] = *(const bf16x8*)(g.A + (size_t)(bm + row) * K + k0 + ch);
            *(bf16x8*)&Bs[row][ch] = *(const bf16x8*)(g.Bt + (size_t)(bn + row) * K + k0 + ch);
        }
        __syncthreads();
#pragma unroll
        for (int kc = 0; kc < 2; kc++) {
            bf16x8 af[4], bfr[4];
#pragma unroll
            for (int i = 0; i < 4; i++) {
                af[i]  = *(const bf16x8*)&As[wm + i * 16 + li][kc * 32 + quad * 8];
                bfr[i] = *(const bf16x8*)&Bs[wn + i * 16 + li][kc * 32 + quad * 8];
            }
#pragma unroll
            for (int mi = 0; mi < 4; mi++)
#pragma unroll
                for (int ni = 0; ni < 4; ni++)
                    acc[mi][ni] = __builtin_amdgcn_mfma_f32_16x16x32_bf16(
                        af[mi], bfr[ni], acc[mi][ni], 0, 0, 0);
        }
        __syncthreads();
    }

    if (g.mode == 1) {
        if (bn >= 1024) {
            // -------- V block: LDS-transposed coalesced V^T store --------
            const int batch = (bm < g.zsplit) ? 0 : 1;
            bf16* kb = batch ? g.kb1 : g.kb0;
            const int brow = bm - batch * g.zsplit;
            const int vc0 = bn - 1024;
            bf16 (*T)[136] = (bf16(*)[136])&As[0][0];   // 64x136 fits in As
            const int c = t >> 2, seg = t & 3;           // c: V^T row, seg: 64B
#pragma unroll
            for (int p = 0; p < 2; p++) {
                if ((w >> 1) == p) {                     // waves owning cols p*64..
#pragma unroll
                    for (int mi = 0; mi < 4; mi++)
#pragma unroll
                        for (int ni = 0; ni < 4; ni++)
#pragma unroll
                            for (int r = 0; r < 4; r++)
                                T[ni * 16 + li][wm + mi * 16 + quad * 4 + r] =
                                    f2b(acc[mi][ni][r]);
                }
                __syncthreads();
                bf16* dst = kb + (size_t)1024 * g.zrows
                            + (size_t)(vc0 + p * 64 + c) * g.zrows + brow + seg * 32;
#pragma unroll
                for (int j = 0; j < 4; j++)
                    *(bf16x8*)(dst + j * 8) = *(const bf16x8*)&T[c][seg * 32 + j * 8];
                __syncthreads();
            }
            return;
        }
        // -------- K block: verified coalesced row-major store --------
#pragma unroll
        for (int mi = 0; mi < 4; mi++)
#pragma unroll
            for (int r = 0; r < 4; r++) {
                const int row = bm + wm + mi * 16 + quad * 4 + r;
                bf16* kb = (row < g.zsplit) ? g.kb0 : g.kb1;
                const int lrow = (row < g.zsplit) ? row : row - g.zsplit;
#pragma unroll
                for (int ni = 0; ni < 4; ni++) {
                    const int col = bn + wn + ni * 16 + li;
                    kb[(size_t)lrow * 1024 + col] = f2b(acc[mi][ni][r]);
                }
            }
        return;
    }

#pragma unroll
    for (int mi = 0; mi < 4; mi++)
#pragma unroll
        for (int r = 0; r < 4; r++) {
            const int row = bm + wm + mi * 16 + quad * 4 + r;
#pragma unroll
            for (int ni = 0; ni < 4; ni++) {
                const int col = bn + wn + ni * 16 + li;
                float v = acc[mi][ni][r];
                if (g.bias) v += ldx(g.bias, col, isb);
                if (g.res)  v += ldx(g.res, (size_t)row * g.N + col, g.res_ext ? isb : true);
                stx(g.C, (size_t)row * g.N + col, g.c_ext ? isb : true, v);
            }
        }
}

// ---------------------------------------------------------------------------
// Round-10 verified: 64x64-tile mode-0 GEMM for the three standalone GEMMs
// (SA-oproj, CA-q, CA-oproj), grid (16,64) = 4 blocks/CU. WIN: −21.6 µs.
// ---------------------------------------------------------------------------
__global__ __launch_bounds__(256) void gemm_t64(
    const bf16* __restrict__ A, const bf16* __restrict__ Bt,
    void* __restrict__ C, int c_ext,
    const void* __restrict__ bias,
    const void* __restrict__ res, int res_ext, int N,
    const int* __restrict__ flagp) {

    const int K = 1024;
    const bool isb = (*flagp != 0);

    __shared__ bf16 As[64][72];
    __shared__ bf16 Bs[64][72];

    const int t = threadIdx.x;
    const int w = t >> 6, lane = t & 63, li = lane & 15, quad = lane >> 4;
    const int wm = (w & 1) * 32, wn = (w >> 1) * 32;
    const int bm = blockIdx.y * 64, bn = blockIdx.x * 64;

    f32x4 acc[2][2];
#pragma unroll
    for (int mi = 0; mi < 2; mi++)
#pragma unroll
        for (int ni = 0; ni < 2; ni++)
#pragma unroll
            for (int r = 0; r < 4; r++) acc[mi][ni][r] = 0.f;

    for (int k0 = 0; k0 < K; k0 += 64) {
#pragma unroll
        for (int c = 0; c < 2; c++) {
            const int d = c * 256 + t;
            const int row = d >> 3, ch = (d & 7) * 8;
            *(bf16x8*)&As[row][ch] = *(const bf16x8*)(A + (size_t)(bm + row) * K + k0 + ch);
            *(bf16x8*)&Bs[row][ch] = *(const bf16x8*)(Bt + (size_t)(bn + row) * K + k0 + ch);
        }
        __syncthreads();
#pragma unroll
        for (int kc = 0; kc < 2; kc++) {
            bf16x8 af[2], bfr[2];
#pragma unroll
            for (int mi = 0; mi < 2; mi++)
                af[mi] = *(const bf16x8*)&As[wm + mi * 16 + li][kc * 32 + quad * 8];
#pragma unroll
            for (int ni = 0; ni < 2; ni++)
                bfr[ni] = *(const bf16x8*)&Bs[wn + ni * 16 + li][kc * 32 + quad * 8];
#pragma unroll
            for (int mi = 0; mi < 2; mi++)
#pragma unroll
                for (int ni = 0; ni < 2; ni++)
                    acc[mi][ni] = __builtin_amdgcn_mfma_f32_16x16x32_bf16(
                        af[mi], bfr[ni], acc[mi][ni], 0, 0, 0);
        }
        __syncthreads();
    }

#pragma unroll
    for (int mi = 0; mi < 2; mi++)
#pragma unroll
        for (int r = 0; r < 4; r++) {
            const int row = bm + wm + mi * 16 + quad * 4 + r;
#pragma unroll
            for (int ni = 0; ni < 2; ni++) {
                const int col = bn + wn + ni * 16 + li;
                float v = acc[mi][ni][r];
                if (bias) v += ldx(bias, col, isb);
                if (res)  v += ldx(res, (size_t)row * N + col, res_ext ? isb : true);
                stx(C, (size_t)row * N + col, c_ext ? isb : true, v);
            }
        }
}

// ---------------------------------------------------------------------------
// Slow-path MFMA GEMM (round-7 verified, used only if workspace is small).
// ---------------------------------------------------------------------------
__global__ __launch_bounds__(256) void gemm_mfma(
    const bf16* __restrict__ A, long a_bs, const void* __restrict__ W,
    void* __restrict__ C, size_t c_off, long c_bs, int c_ext,
    const void* __restrict__ bias,
    const void* __restrict__ res, size_t res_off, long res_bs, int res_ext,
    int K, int N, int mode, int R,
    bf16* __restrict__ kb0, bf16* __restrict__ kb1,
    const int* __restrict__ flagp) {

    const bool isb = (*flagp != 0);
    const bool resb = res_ext ? isb : true;
    const bool cb = c_ext ? isb : true;
    const int z = blockIdx.z;

    const bf16* Az = A + (size_t)z * a_bs;
    const size_t coz = c_off + (size_t)z * c_bs;
    const size_t roz = res_off + (size_t)z * res_bs;

    __shared__ bf16 As[64][72];
    __shared__ bf16 Bs[64][72];

    const int t = threadIdx.x;
    const int w = t >> 6, lane = t & 63, li = lane & 15, quad = lane >> 4;
    const int wm = (w & 1) * 32, wn = (w >> 1) * 32;
    const int bm = blockIdx.y * 64, bn = blockIdx.x * 64;

    f32x4 acc[2][2];
#pragma unroll
    for (int mi = 0; mi < 2; mi++)
#pragma unroll
        for (int ni = 0; ni < 2; ni++)
#pragma unroll
            for (int r = 0; r < 4; r++) acc[mi][ni][r] = 0.f;

    for (int k0 = 0; k0 < K; k0 += 64) {
#pragma unroll
        for (int c = 0; c < 2; c++) {
            const int lin = t * 16 + c * 8;
            const int row = lin >> 6, kk = lin & 63;
            *(bf16x8*)&As[row][kk] = *(const bf16x8*)(Az + (size_t)(bm + row) * K + k0 + kk);
        }
#pragma unroll
        for (int c = 0; c < 2; c++) {
            const int lin = t * 16 + c * 8;
            const int kk = lin >> 6, n0 = lin & 63;
            float v[8];
            ldx8(W, (size_t)(k0 + kk) * N + bn + n0, isb, v);
            const int st = t & 7;
#pragma unroll
            for (int i = 0; i < 8; i++) {
                const int ii = (i + st) & 7;
                Bs[n0 + ii][kk] = f2b(v[ii]);
            }
        }
        __syncthreads();
#pragma unroll
        for (int kc = 0; kc < 2; kc++) {
            bf16x8 af[2], bfr[2];
#pragma unroll
            for (int mi = 0; mi < 2; mi++)
                af[mi] = *(const bf16x8*)&As[wm + mi * 16 + li][kc * 32 + quad * 8];
#pragma unroll
            for (int ni = 0; ni < 2; ni++)
                bfr[ni] = *(const bf16x8*)&Bs[wn + ni * 16 + li][kc * 32 + quad * 8];
#pragma unroll
            for (int mi = 0; mi < 2; mi++)
#pragma unroll
                for (int ni = 0; ni < 2; ni++)
                    acc[mi][ni] = __builtin_amdgcn_mfma_f32_16x16x32_bf16(
                        af[mi], bfr[ni], acc[mi][ni], 0, 0, 0);
        }
        __syncthreads();
    }

    if (mode == 1) {
        bf16* kb = z ? kb1 : kb0;
#pragma unroll
        for (int mi = 0; mi < 2; mi++)
#pragma unroll
            for (int r = 0; r < 4; r++) {
                const int row = bm + wm + mi * 16 + quad * 4 + r;
#pragma unroll
                for (int ni = 0; ni < 2; ni++) {
                    const int col = bn + wn + ni * 16 + li;
                    const float v = acc[mi][ni][r];
                    if (col < 1024)
                        kb[(size_t)row * 1024 + col] = f2b(v);
                    else
                        kb[(size_t)1024 * R + (size_t)(col - 1024) * R + row] = f2b(v);
                }
            }
        return;
    }

#pragma unroll
    for (int mi = 0; mi < 2; mi++)
#pragma unroll
        for (int r = 0; r < 4; r++) {
            const int row = bm + wm + mi * 16 + quad * 4 + r;
#pragma unroll
            for (int ni = 0; ni < 2; ni++) {
                const int col = bn + wn + ni * 16 + li;
                float v = acc[mi][ni][r];
                if (bias) v += ldx(bias, col, isb);
                if (res)  v += ldx(res, roz + (size_t)row * N + col, resb);
                stx(C, coz + (size_t)row * N + col, cb, v);
            }
        }
}

// ---------------------------------------------------------------------------
// attn_flash: round-0 verified body — best measured (134.6 µs SA). Five
// variants failed; frozen. (Codegen lottery across builds: ±5 µs.)
// ---------------------------------------------------------------------------
__global__ __launch_bounds__(64) void attn_flash(
    const bf16* __restrict__ qb, const bf16* __restrict__ kv0,
    const bf16* __restrict__ kv1,
    const void* __restrict__ rel_emb, bf16* __restrict__ out,
    long qo_bs, long out_bs, int m, int rel_off, const int* __restrict__ flagp) {

    const float SC = 0.125f * 1.44269504f;
    const bool isb = (*flagp != 0);
    const int id = blockIdx.x;
    const int xcd = id & 7;
    const int slot = id >> 3;
    const int c = (slot >> 6) * 8 + xcd;
    const int h = c & 15, z = c >> 4;
    const int q0 = (slot & 63) * 32;
    const int t = threadIdx.x;
    const int li = t & 15, quad = t >> 4;

    const bf16* qz = qb + (size_t)z * qo_bs;
    bf16* oz = out + (size_t)z * out_bs;
    const bf16* kb = z ? kv1 : kv0;
    const bf16* vtb = kb + (size_t)m * 1024;

    __shared__ float bias_s[32];
    __shared__ float tab[2080];
    __shared__ bf16 Ps[16][40];

    if (t < 32) bias_s[t] = ldx(rel_emb, t * 16 + h, isb) * SC - 40.0f;
    __syncthreads();

    const int tsz = m + 31;
    for (int i = t; i < tsz; i += 64) {
        const int rel = i - 31 - q0 + rel_off;
        const int ab = rel < 0 ? -rel : rel;
        int bucket = rel >= 0 ? 16 : 0;
        if (ab < 8) {
            bucket += ab;
        } else {
            const int p = 31 - __clz(ab);
            const int k2 = 2 * p + ((ab * ab >= (1 << (2 * p + 1))) ? 1 : 0);
            const int val = k2 + 2;
            bucket += (val > 15) ? 15 : val;
        }
        tab[i] = bias_s[bucket];
    }
    __syncthreads();

    bf16x8 aq[2][2];
#pragma unroll
    for (int g = 0; g < 2; g++)
#pragma unroll
        for (int kc = 0; kc < 2; kc++)
            aq[g][kc] = *(const bf16x8*)(qz + (size_t)(q0 + g * 16 + li) * 1024
                                         + h * 64 + kc * 32 + quad * 8);

    bf16x8 ones;
#pragma unroll
    for (int j = 0; j < 8; j++) ((short*)&ones)[j] = 0x3F80;

    f32x4 o[2][4], lac[2];
#pragma unroll
    for (int g = 0; g < 2; g++) {
#pragma unroll
        for (int r = 0; r < 4; r++) lac[g][r] = 0.f;
#pragma unroll
        for (int nb = 0; nb < 4; nb++)
#pragma unroll
            for (int r = 0; r < 4; r++) o[g][nb][r] = 0.f;
    }

    for (int j0 = 0; j0 < m; j0 += 32) {
        bf16x8 kf[4], vf[4];
#pragma unroll
        for (int nb = 0; nb < 2; nb++)
#pragma unroll
            for (int kc = 0; kc < 2; kc++)
                kf[nb * 2 + kc] = *(const bf16x8*)(
                    kb + (size_t)(j0 + nb * 16 + li) * 1024 + h * 64 + kc * 32 + quad * 8);
#pragma unroll
        for (int nb = 0; nb < 4; nb++)
            vf[nb] = *(const bf16x8*)(
                vtb + (size_t)(h * 64 + nb * 16 + li) * m + j0 + quad * 8);

#pragma unroll
        for (int g = 0; g < 2; g++) {
            f32x4 s[2];
            __builtin_amdgcn_s_setprio(1);
#pragma unroll
            for (int nb = 0; nb < 2; nb++) {
                f32x4 a;
#pragma unroll
                for (int r = 0; r < 4; r++) a[r] = 0.f;
#pragma unroll
                for (int kc = 0; kc < 2; kc++)
                    a = __builtin_amdgcn_mfma_f32_16x16x32_bf16(aq[g][kc], kf[nb * 2 + kc],
                                                                a, 0, 0, 0);
                s[nb] = a;
            }
            __builtin_amdgcn_s_setprio(0);
#pragma unroll
            for (int nb = 0; nb < 2; nb++)
#pragma unroll
                for (int r = 0; r < 4; r++) {
                    const int ti = j0 + nb * 16 + li + 31 - (g * 16 + quad * 4 + r);
                    s[nb][r] = exp2f(fmaf(s[nb][r], SC, tab[ti]));
                }
#pragma unroll
            for (int nb = 0; nb < 2; nb++)
#pragma unroll
                for (int r = 0; r < 4; r++)
                    Ps[quad * 4 + r][nb * 16 + li] = f2b(s[nb][r]);
            const bf16x8 ap = *(const bf16x8*)&Ps[li][quad * 8];
            __builtin_amdgcn_s_setprio(1);
#pragma unroll
            for (int nb = 0; nb < 4; nb++)
                o[g][nb] = __builtin_amdgcn_mfma_f32_16x16x32_bf16(ap, vf[nb],
                                                                   o[g][nb], 0, 0, 0);
            lac[g] = __builtin_amdgcn_mfma_f32_16x16x32_bf16(ap, ones, lac[g], 0, 0, 0);
            __builtin_amdgcn_s_setprio(0);
        }
    }

#pragma unroll
    for (int g = 0; g < 2; g++)
#pragma unroll
        for (int r = 0; r < 4; r++) {
            const float inv = 1.0f / lac[g][r];
            const int qi = q0 + g * 16 + quad * 4 + r;
#pragma unroll
            for (int nb = 0; nb < 4; nb++)
                oz[(size_t)qi * 1024 + h * 64 + nb * 16 + li] = f2b(o[g][nb][r] * inv);
        }
}

// ---------------------------------------------------------------------------
// Launcher. Fast path (ws >= 56 MB + 256; measured ws = 256 MB):
//   F_A|F_B|F_C (24 MB) + WT (8) + F_X (8) + F_Y (6) + WT2 (8) = 54 MB.
// Round-10 schedule (best: 460.3 µs) with the two prologue LNs merged into
// one ln_pro dispatch. Big dispatch back on 128^2 gemm_fused (round-11's
// 64^2 regressed). Fallback: round-7 plan (24 MB).
// ---------------------------------------------------------------------------
extern "C" void kernel_launch(void* const* d_in, const int* in_sizes, int n_in,
                              void* d_out, int out_size, void* d_ws, size_t ws_size,
                              hipStream_t stream) {
    const long M1 = 1024 * 1024;
    const long M2 = 2 * 1024 * 1024;
    const long M4 = 4 * 1024 * 1024;
    if (ws_size < 24u * 1024 * 1024 + 256) return;

    const void* x      = d_in[0];
    const void* ctx    = d_in[1];
    const void* sa_ng  = d_in[2];
    const void* sa_nb  = d_in[3];
    const void* sa_ncg = d_in[4];
    const void* sa_ncb = d_in[5];
    const void* sa_wq  = d_in[6];
    const void* sa_wkv = d_in[7];
    const void* sa_wo  = d_in[8];
    const void* sa_bo  = d_in[9];
    const void* sa_rel = d_in[10];
    const void* ca_ng  = d_in[11];
    const void* ca_nb  = d_in[12];
    const void* ca_ncg = d_in[13];
    const void* ca_ncb = d_in[14];
    const void* ca_wq  = d_in[15];
    const void* ca_wkv = d_in[16];
    const void* ca_wo  = d_in[17];
    const void* ca_bo  = d_in[18];
    const void* ca_rel = d_in[19];

    int* flag = (int*)d_ws;
    bf16* F_A = (bf16*)((char*)d_ws + 256);
    bf16* F_B = F_A + M4;
    bf16* F_C = F_B + M4;
    bf16* WT  = F_C + M4;                // fast path only (SA weights)
    bf16* F_X = WT + M4;                 // fast path only (xn buffer)
    bf16* F_Y = F_X + M4;                // fast path only (ctx-LN + CA K/V)
    bf16* WT2 = F_Y + 3 * M1;            // fast path only (CA weights)
    bf16* qd  = (bf16*)d_out;            // d_out as bf16 scratch (q / ao)

    sniff_kernel<<<1, 256, 0, stream>>>(x, flag);

    if (ws_size >= 56u * 1024 * 1024 + 256) {
        bf16* WTq  = WT;                 // [1024][1024]
        bf16* WTkv = WT + M1;            // [2048][1024]
        bf16* WTo  = WT + 3 * M1;        // [1024][1024]
        bf16* WT2q  = WT2;
        bf16* WT2kv = WT2 + M1;
        bf16* WT2o  = WT2 + 3 * M1;
        bf16* CAK0 = F_Y + M1;           // z0: K[512][1024] + V^T[1024][512]
        bf16* CAK1 = F_Y + 2 * M1;       // z1: same layout

        // ===== prologue: all weight transposes + merged input LNs =====
        wconv8_kernel<<<dim3(16, 16, 8), 256, 0, stream>>>(
            sa_wq, sa_wkv, sa_wo, ca_wq, ca_wkv, ca_wo,
            WTq, WTkv, WTo, WT2q, WT2kv, WT2o, flag);
        ln_pro_kernel<<<dim3(2560, 1, 2), 256, 0, stream>>>(
            x, ctx, sa_ng, sa_nb, sa_ncg, sa_ncb, ca_ncg, ca_ncb,
            F_X, F_B, F_Y, flag);

        // ===== BIG (128^2): SA-q + SA-kv + CA-kv =====
        {
            GArgs gq = {};
            gq.A = F_X; gq.Bt = WTq; gq.C = qd;
            gq.N = 1024; gq.nbx = 8; gq.nby = 32;
            GArgs gkv = {};
            gkv.A = F_B; gkv.Bt = WTkv;
            gkv.N = 2048; gkv.mode = 1; gkv.zsplit = 2048; gkv.zrows = 2048;
            gkv.kb0 = F_A; gkv.kb1 = F_C; gkv.nbx = 16; gkv.nby = 32;
            GArgs gca = {};
            gca.A = F_Y; gca.Bt = WT2kv;
            gca.N = 2048; gca.mode = 1; gca.zsplit = 512; gca.zrows = 512;
            gca.kb0 = CAK0; gca.kb1 = CAK1; gca.nbx = 16; gca.nby = 8;
            gemm_fused<<<dim3(40, 32), 256, 0, stream>>>(gq, gkv, gca, flag);
        }

        // ===== self-attention + o-proj =====
        attn_flash<<<dim3(2048), 64, 0, stream>>>(
            qd, F_A, F_C, sa_rel, qd, M2, M2, 2048, 0, flag);
        gemm_t64<<<dim3(16, 64), 256, 0, stream>>>(
            qd, WTo, F_B, 0, sa_bo, x, 1, 1024, flag);

        // ===== cross-attention =====
        ln_dual_kernel<<<dim3(2048, 1, 2), 256, 0, stream>>>(
            F_B, 0, M2, 0, ca_ng, ca_nb, nullptr, nullptr, F_X, nullptr, M2, flag);
        gemm_t64<<<dim3(16, 64), 256, 0, stream>>>(
            F_X, WT2q, qd, 0, nullptr, nullptr, 0, 1024, flag);
        attn_flash<<<dim3(2048), 64, 0, stream>>>(
            qd, CAK0, CAK1, ca_rel, F_C, M2, M2, 512, 1536, flag);
        gemm_t64<<<dim3(16, 64), 256, 0, stream>>>(
            F_C, WT2o, d_out, 1, ca_bo, F_B, 0, 1024, flag);
        return;
    }

    // ================= fallback: round-7 verified plan =================
    ln_dual_kernel<<<dim3(2048, 1, 2), 256, 0, stream>>>(
        x, 0, M2, 1, sa_ng, sa_nb, sa_ncg, sa_ncb, F_A, F_B, M2, flag);
    gemm_mfma<<<dim3(16, 32, 2), 256, 0, stream>>>(
        F_A, M2, sa_wq, qd, 0, M2, 0, nullptr, nullptr, 0, 0, 0,
        1024, 1024, 0, 0, nullptr, nullptr, flag);
    gemm_mfma<<<dim3(32, 32, 2), 256, 0, stream>>>(
        F_B, M2, sa_wkv, nullptr, 0, 0, 0, nullptr, nullptr, 0, 0, 0,
        1024, 2048, 1, 2048, F_A, F_C, flag);
    attn_flash<<<dim3(2048), 64, 0, stream>>>(
        qd, F_A, F_C, sa_rel, qd, M2, M2, 2048, 0, flag);
    gemm_mfma<<<dim3(16, 32, 2), 256, 0, stream>>>(
        qd, M2, sa_wo, F_B, 0, M2, 0, sa_bo, x, 0, M2, 1,
        1024, 1024, 0, 0, nullptr, nullptr, flag);

    ln_dual_kernel<<<dim3(2048, 1, 2), 256, 0, stream>>>(
        F_B, 0, M2, 0, ca_ng, ca_nb, nullptr, nullptr, F_A, nullptr, M2, flag);
    ln_dual_kernel<<<dim3(512, 1, 2), 256, 0, stream>>>(
        ctx, 0, 512 * 1024, 1, ca_ncg, ca_ncb, nullptr, nullptr,
        F_C, nullptr, 512 * 1024, flag);
    gemm_mfma<<<dim3(16, 32, 2), 256, 0, stream>>>(
        F_A, M2, ca_wq, qd, 0, M2, 0, nullptr, nullptr, 0, 0, 0,
        1024, 1024, 0, 0, nullptr, nullptr, flag);
    gemm_mfma<<<dim3(32, 8, 2), 256, 0, stream>>>(
        F_C, 512 * 1024, ca_wkv, nullptr, 0, 0, 0, nullptr, nullptr, 0, 0, 0,
        1024, 2048, 1, 512, F_A, F_A + M1, flag);
    attn_flash<<<dim3(2048), 64, 0, stream>>>(
        qd, F_A, F_A + M1, ca_rel, F_C, M2, M2, 512, 1536, flag);
    gemm_mfma<<<dim3(16, 32, 2), 256, 0, stream>>>(
        F_C, M2, ca_wo, d_out, 0, M2, 1, ca_bo, F_B, 0, M2, 0,
        1024, 1024, 0, 0, nullptr, nullptr, flag);
}

// Round 13
// 455.562 us; speedup vs baseline: 1.0361x; 1.0077x over previous
//
#include <hip/hip_runtime.h>
#include <hip/hip_bf16.h>

typedef __hip_bfloat16 bf16;
typedef __attribute__((ext_vector_type(8))) short bf16x8;   // 8 bf16 (4 VGPRs)
typedef __attribute__((ext_vector_type(4))) float f32x4;    // MFMA accum

__device__ __forceinline__ float b2f(bf16 v) { return __bfloat162float(v); }
__device__ __forceinline__ bf16 f2b(float v) { return __float2bfloat16(v); }

// Scalar load/store from an external buffer whose dtype is decided by isb.
__device__ __forceinline__ float ldx(const void* p, size_t i, bool isb) {
    return isb ? b2f(((const bf16*)p)[i]) : ((const float*)p)[i];
}
__device__ __forceinline__ void stx(void* p, size_t i, bool isb, float v) {
    if (isb) ((bf16*)p)[i] = f2b(v);
    else     ((float*)p)[i] = v;
}
// Vector (8-elem) external load; i must be a multiple of 8.
__device__ __forceinline__ void ldx8(const void* p, size_t i, bool isb, float* o) {
    if (isb) {
        const bf16x8 v = *(const bf16x8*)((const bf16*)p + i);
#pragma unroll
        for (int j = 0; j < 8; j++) o[j] = b2f(((const bf16*)&v)[j]);
    } else {
        const float4 v0 = *(const float4*)((const float*)p + i);
        const float4 v1 = *(const float4*)((const float*)p + i + 4);
        o[0]=v0.x; o[1]=v0.y; o[2]=v0.z; o[3]=v0.w;
        o[4]=v1.x; o[5]=v1.y; o[6]=v1.z; o[7]=v1.w;
    }
}

// ---------------------------------------------------------------------------
// Dtype sniffer (verified round 3): decides fp32 vs bf16 external data.
// ---------------------------------------------------------------------------
__global__ void sniff_kernel(const void* __restrict__ x, int* __restrict__ flag) {
    const unsigned* w = (const unsigned*)x;
    const int t = threadIdx.x;
    int cnt = 0;
#pragma unroll
    for (int i = 0; i < 4; i++) {
        const unsigned word = w[t * 4 + i];
        const int e = (word >> 23) & 0xFF;
        cnt += (e >= 192) ? 1 : 0;
    }
    __shared__ int red[4];
#pragma unroll
    for (int o = 32; o > 0; o >>= 1) cnt += __shfl_down(cnt, o);
    if ((t & 63) == 0) red[t >> 6] = cnt;
    __syncthreads();
    if (t == 0) flag[0] = ((red[0] + red[1] + red[2] + red[3]) >= 512) ? 1 : 0;
}

// ---------------------------------------------------------------------------
// ROUND 13: merged PROLOGUE kernel — weight transposes (both phases) AND
// both input LNs in ONE dispatch. Linear grid, block-uniform demux:
//   bid 0..2047    : wconv work, decode bx=bid&15, by=(bid>>4)&15, zz=bid>>8
//   bid 2048..7167 : LN work, lnid=bid-2048; z=lnid>=2560; row-id=lnid%2560
//     row 0..2047 -> x rows (dual out F_X/F_B); 2048..2559 -> ctx rows (F_Y)
// wconv is LDS/VALU-bound, LN is HBM-bound -> complementary-resource overlap
// (m114: co-resident time ~ max, not sum). Each block runs exactly one path
// so __syncthreads stays block-uniform. LDS = union (wconv's 64x65 floats).
// ---------------------------------------------------------------------------
__global__ void prologue_kernel(
    // wconv inputs/outputs
    const void* __restrict__ Wq,  const void* __restrict__ Wkv,
    const void* __restrict__ Wo,  const void* __restrict__ Wq2,
    const void* __restrict__ Wkv2, const void* __restrict__ Wo2,
    bf16* __restrict__ WTq,  bf16* __restrict__ WTkv,  bf16* __restrict__ WTo,
    bf16* __restrict__ WTq2, bf16* __restrict__ WTkv2, bf16* __restrict__ WTo2,
    // LN inputs/outputs
    const void* __restrict__ x, const void* __restrict__ ctx,
    const void* __restrict__ g1, const void* __restrict__ b1,
    const void* __restrict__ g2, const void* __restrict__ b2,
    const void* __restrict__ g3, const void* __restrict__ b3,
    bf16* __restrict__ outX, bf16* __restrict__ outB, bf16* __restrict__ outY,
    const int* __restrict__ flagp) {

    const bool isb = (*flagp != 0);
    const int bid = blockIdx.x;
    const int t = threadIdx.x;

    __shared__ __align__(16) char smem[16640];   // 64*65*4 = 16640 B

    if (bid < 2048) {
        // ================= wconv path (verified wconv8 body) =============
        float (*T)[65] = (float(*)[65])smem;
        const int bx = bid & 15, by = (bid >> 4) & 15, z = bid >> 8;
        const int zz = z & 3;
        const bool ca = z >= 4;
        const void* W = ca ? ((zz == 0) ? Wq2 : (zz == 3) ? Wo2 : Wkv2)
                           : ((zz == 0) ? Wq  : (zz == 3) ? Wo  : Wkv);
        bf16* Wt      = ca ? ((zz == 0) ? WTq2 : (zz == 3) ? WTo2 : WTkv2)
                           : ((zz == 0) ? WTq  : (zz == 3) ? WTo  : WTkv);
        const int N   = (zz == 1 || zz == 2) ? 2048 : 1024;
        const int K = 1024;
        const int n0 = bx * 64 + ((zz == 2) ? 1024 : 0);
        const int k0 = by * 64;
        const int rr = t >> 3, c8 = (t & 7) * 8;
#pragma unroll
        for (int i = 0; i < 2; i++) {
            const int row = rr + i * 32;
            float v[8];
            ldx8(W, (size_t)(k0 + row) * N + n0 + c8, isb, v);
#pragma unroll
            for (int j = 0; j < 8; j++) T[row][c8 + j] = v[j];
        }
        __syncthreads();
#pragma unroll
        for (int i = 0; i < 2; i++) {
            const int row = rr + i * 32;   // n-index within tile
            bf16x8 ov;
#pragma unroll
            for (int j = 0; j < 8; j++) ((bf16*)&ov)[j] = f2b(T[c8 + j][row]);
            *(bf16x8*)(Wt + (size_t)(n0 + row) * K + k0 + c8) = ov;
        }
        return;
    }

    // =================== LN path (verified ln_pro body) ==================
    const int F = 1024;
    float* red1 = (float*)smem;
    float* red2 = (float*)smem + 4;
    const int lnid = bid - 2048;             // 0..5119
    const int z = (lnid >= 2560) ? 1 : 0;
    const int bid2 = lnid - z * 2560;        // 0..2559
    const bool isCtx = bid2 >= 2048;
    const int row = isCtx ? bid2 - 2048 : bid2;
    const void* in = isCtx ? ctx : x;
    const size_t base = (isCtx ? (size_t)z * (512 * 1024)
                               : (size_t)z * (2048 * 1024)) + (size_t)row * F;

    float v[4];
    float s = 0.f;
#pragma unroll
    for (int i = 0; i < 4; i++) { v[i] = ldx(in, base + t + 256 * i, isb); s += v[i]; }

#pragma unroll
    for (int o = 32; o > 0; o >>= 1) s += __shfl_down(s, o);
    if ((t & 63) == 0) red1[t >> 6] = s;
    __syncthreads();
    const float mean = (red1[0] + red1[1] + red1[2] + red1[3]) * (1.0f / F);

    float ss = 0.f;
#pragma unroll
    for (int i = 0; i < 4; i++) { float d = v[i] - mean; ss += d * d; }
#pragma unroll
    for (int o = 32; o > 0; o >>= 1) ss += __shfl_down(ss, o);
    if ((t & 63) == 0) red2[t >> 6] = ss;
    __syncthreads();
    const float var = (red2[0] + red2[1] + red2[2] + red2[3]) * (1.0f / F);
    const float rn = rsqrtf(var + 1e-5f);

    if (isCtx) {
        const size_t obase = (size_t)z * (512 * 1024) + (size_t)row * F;
#pragma unroll
        for (int i = 0; i < 4; i++) {
            const int idx = t + 256 * i;
            const float nv = (v[i] - mean) * rn;
            outY[obase + idx] = f2b(nv * ldx(g3, idx, isb) + ldx(b3, idx, isb));
        }
    } else {
        const size_t obase = (size_t)z * (2048 * 1024) + (size_t)row * F;
#pragma unroll
        for (int i = 0; i < 4; i++) {
            const int idx = t + 256 * i;
            const float nv = (v[i] - mean) * rn;
            outX[obase + idx] = f2b(nv * ldx(g1, idx, isb) + ldx(b1, idx, isb));
            outB[obase + idx] = f2b(nv * ldx(g2, idx, isb) + ldx(b2, idx, isb));
        }
    }
}

// ---------------------------------------------------------------------------
// LayerNorm over F=1024, batch-fused via grid.z (per-batch strides in elems).
// Used for the mid-pipeline CA-x LN (and the fallback path).
// ---------------------------------------------------------------------------
__global__ void ln_dual_kernel(const void* __restrict__ in, size_t in_off, long in_bs,
                               int in_ext,
                               const void* __restrict__ g1, const void* __restrict__ b1,
                               const void* __restrict__ g2, const void* __restrict__ b2,
                               bf16* __restrict__ out1, bf16* __restrict__ out2,
                               long out_bs, const int* __restrict__ flagp) {
    const int F = 1024;
    const bool isb = (*flagp != 0);
    const bool inb = in_ext ? isb : true;
    const int row = blockIdx.x;
    const int z = blockIdx.z;
    const int t = threadIdx.x;
    const size_t base = in_off + (size_t)z * in_bs + (size_t)row * F;
    const size_t obase = (size_t)z * out_bs + (size_t)row * F;

    float v[4];
    float s = 0.f;
#pragma unroll
    for (int i = 0; i < 4; i++) { v[i] = ldx(in, base + t + 256 * i, inb); s += v[i]; }

    __shared__ float red1[4];
    __shared__ float red2[4];
#pragma unroll
    for (int o = 32; o > 0; o >>= 1) s += __shfl_down(s, o);
    if ((t & 63) == 0) red1[t >> 6] = s;
    __syncthreads();
    const float mean = (red1[0] + red1[1] + red1[2] + red1[3]) * (1.0f / F);

    float ss = 0.f;
#pragma unroll
    for (int i = 0; i < 4; i++) { float d = v[i] - mean; ss += d * d; }
#pragma unroll
    for (int o = 32; o > 0; o >>= 1) ss += __shfl_down(ss, o);
    if ((t & 63) == 0) red2[t >> 6] = ss;
    __syncthreads();
    const float var = (red2[0] + red2[1] + red2[2] + red2[3]) * (1.0f / F);
    const float rn = rsqrtf(var + 1e-5f);

#pragma unroll
    for (int i = 0; i < 4; i++) {
        const int idx = t + 256 * i;
        const float nv = (v[i] - mean) * rn;
        out1[obase + idx] = f2b(nv * ldx(g1, idx, isb) + ldx(b1, idx, isb));
        if (out2) out2[obase + idx] = f2b(nv * ldx(g2, idx, isb) + ldx(b2, idx, isb));
    }
}

// ---------------------------------------------------------------------------
// Grouped GEMM args. C = A[R,1024] @ Bt^T, 128x128 tile, BK=64, 4 waves.
// ---------------------------------------------------------------------------
struct GArgs {
    const bf16* A; const bf16* Bt; void* C;
    const void* bias; const void* res;
    bf16* kb0; bf16* kb1;
    int c_ext, res_ext, N, mode, zsplit, zrows, nbx, nby;
};

// ---------------------------------------------------------------------------
// Reg-staged grouped GEMM (verified body, padded LDS). Mode-1 V-half writes
// V^T via LDS transpose (round-8 win). Used for the BIG 3-slot dispatch at
// 128^2 tiles / 3.5 blocks/CU — round 11 proved 64^2 tiles REGRESS here.
// ---------------------------------------------------------------------------
__global__ __launch_bounds__(256) void gemm_fused(GArgs ga, GArgs gb, GArgs gc,
                                                  const int* __restrict__ flagp) {
    int bx = (int)blockIdx.x;
    GArgs g;
    if (bx < ga.nbx) { g = ga; }
    else if (bx < ga.nbx + gb.nbx) { g = gb; bx -= ga.nbx; }
    else { g = gc; bx -= ga.nbx + gb.nbx; }
    const int by = (int)blockIdx.y;
    if (by >= g.nby) return;               // block-uniform: no divergent barrier

    const int K = 1024;
    const bool isb = (*flagp != 0);

    __shared__ bf16 As[128][72];
    __shared__ bf16 Bs[128][72];

    const int t = threadIdx.x;
    const int w = t >> 6, lane = t & 63, li = lane & 15, quad = lane >> 4;
    const int wm = (w & 1) * 64, wn = (w >> 1) * 64;
    const int bm = by * 128, bn = bx * 128;

    f32x4 acc[4][4];
#pragma unroll
    for (int mi = 0; mi < 4; mi++)
#pragma unroll
        for (int ni = 0; ni < 4; ni++)
#pragma unroll
            for (int r = 0; r < 4; r++) acc[mi][ni][r] = 0.f;

    for (int k0 = 0; k0 < K; k0 += 64) {
#pragma unroll
        for (int c = 0; c < 4; c++) {
            const int d = c * 256 + t;
            const int row = d >> 3, ch = (d & 7) * 8;
            *(bf16x8*)&As[row][ch] = *(const bf16x8*)(g.A + (size_t)(bm + row) * K + k0 + ch);
            *(bf16x8*)&Bs[row][ch] = *(const bf16x8*)(g.Bt + (size_t)(bn + row) * K + k0 + ch);
        }
        __syncthreads();
#pragma unroll
        for (int kc = 0; kc < 2; kc++) {
            bf16x8 af[4], bfr[4];
#pragma unroll
            for (int i = 0; i < 4; i++) {
                af[i]  = *(const bf16x8*)&As[wm + i * 16 + li][kc * 32 + quad * 8];
                bfr[i] = *(const bf16x8*)&Bs[wn + i * 16 + li][kc * 32 + quad * 8];
            }
#pragma unroll
            for (int mi = 0; mi < 4; mi++)
#pragma unroll
                for (int ni = 0; ni < 4; ni++)
                    acc[mi][ni] = __builtin_amdgcn_mfma_f32_16x16x32_bf16(
                        af[mi], bfr[ni], acc[mi][ni], 0, 0, 0);
        }
        __syncthreads();
    }

    if (g.mode == 1) {
        if (bn >= 1024) {
            // -------- V block: LDS-transposed coalesced V^T store --------
            const int batch = (bm < g.zsplit) ? 0 : 1;
            bf16* kb = batch ? g.kb1 : g.kb0;
            const int brow = bm - batch * g.zsplit;
            const int vc0 = bn - 1024;
            bf16 (*T)[136] = (bf16(*)[136])&As[0][0];   // 64x136 fits in As
            const int c = t >> 2, seg = t & 3;           // c: V^T row, seg: 64B
#pragma unroll
            for (int p = 0; p < 2; p++) {
                if ((w >> 1) == p) {                     // waves owning cols p*64..
#pragma unroll
                    for (int mi = 0; mi < 4; mi++)
#pragma unroll
                        for (int ni = 0; ni < 4; ni++)
#pragma unroll
                            for (int r = 0; r < 4; r++)
                                T[ni * 16 + li][wm + mi * 16 + quad * 4 + r] =
                                    f2b(acc[mi][ni][r]);
                }
                __syncthreads();
                bf16* dst = kb + (size_t)1024 * g.zrows
                            + (size_t)(vc0 + p * 64 + c) * g.zrows + brow + seg * 32;
#pragma unroll
                for (int j = 0; j < 4; j++)
                    *(bf16x8*)(dst + j * 8) = *(const bf16x8*)&T[c][seg * 32 + j * 8];
                __syncthreads();
            }
            return;
        }
        // -------- K block: verified coalesced row-major store --------
#pragma unroll
        for (int mi = 0; mi < 4; mi++)
#pragma unroll
            for (int r = 0; r < 4; r++) {
                const int row = bm + wm + mi * 16 + quad * 4 + r;
                bf16* kb = (row < g.zsplit) ? g.kb0 : g.kb1;
                const int lrow = (row < g.zsplit) ? row : row - g.zsplit;
#pragma unroll
                for (int ni = 0; ni < 4; ni++) {
                    const int col = bn + wn + ni * 16 + li;
                    kb[(size_t)lrow * 1024 + col] = f2b(acc[mi][ni][r]);
                }
            }
        return;
    }

#pragma unroll
    for (int mi = 0; mi < 4; mi++)
#pragma unroll
        for (int r = 0; r < 4; r++) {
            const int row = bm + wm + mi * 16 + quad * 4 + r;
#pragma unroll
            for (int ni = 0; ni < 4; ni++) {
                const int col = bn + wn + ni * 16 + li;
                float v = acc[mi][ni][r];
                if (g.bias) v += ldx(g.bias, col, isb);
                if (g.res)  v += ldx(g.res, (size_t)row * g.N + col, g.res_ext ? isb : true);
                stx(g.C, (size_t)row * g.N + col, g.c_ext ? isb : true, v);
            }
        }
}

// ---------------------------------------------------------------------------
// Round-10 verified: 64x64-tile mode-0 GEMM for the three standalone GEMMs
// (SA-oproj, CA-q, CA-oproj), grid (16,64) = 4 blocks/CU. WIN: −21.6 µs.
// ---------------------------------------------------------------------------
__global__ __launch_bounds__(256) void gemm_t64(
    const bf16* __restrict__ A, const bf16* __restrict__ Bt,
    void* __restrict__ C, int c_ext,
    const void* __restrict__ bias,
    const void* __restrict__ res, int res_ext, int N,
    const int* __restrict__ flagp) {

    const int K = 1024;
    const bool isb = (*flagp != 0);

    __shared__ bf16 As[64][72];
    __shared__ bf16 Bs[64][72];

    const int t = threadIdx.x;
    const int w = t >> 6, lane = t & 63, li = lane & 15, quad = lane >> 4;
    const int wm = (w & 1) * 32, wn = (w >> 1) * 32;
    const int bm = blockIdx.y * 64, bn = blockIdx.x * 64;

    f32x4 acc[2][2];
#pragma unroll
    for (int mi = 0; mi < 2; mi++)
#pragma unroll
        for (int ni = 0; ni < 2; ni++)
#pragma unroll
            for (int r = 0; r < 4; r++) acc[mi][ni][r] = 0.f;

    for (int k0 = 0; k0 < K; k0 += 64) {
#pragma unroll
        for (int c = 0; c < 2; c++) {
            const int d = c * 256 + t;
            const int row = d >> 3, ch = (d & 7) * 8;
            *(bf16x8*)&As[row][ch] = *(const bf16x8*)(A + (size_t)(bm + row) * K + k0 + ch);
            *(bf16x8*)&Bs[row][ch] = *(const bf16x8*)(Bt + (size_t)(bn + row) * K + k0 + ch);
        }
        __syncthreads();
#pragma unroll
        for (int kc = 0; kc < 2; kc++) {
            bf16x8 af[2], bfr[2];
#pragma unroll
            for (int mi = 0; mi < 2; mi++)
                af[mi] = *(const bf16x8*)&As[wm + mi * 16 + li][kc * 32 + quad * 8];
#pragma unroll
            for (int ni = 0; ni < 2; ni++)
                bfr[ni] = *(const bf16x8*)&Bs[wn + ni * 16 + li][kc * 32 + quad * 8];
#pragma unroll
            for (int mi = 0; mi < 2; mi++)
#pragma unroll
                for (int ni = 0; ni < 2; ni++)
                    acc[mi][ni] = __builtin_amdgcn_mfma_f32_16x16x32_bf16(
                        af[mi], bfr[ni], acc[mi][ni], 0, 0, 0);
        }
        __syncthreads();
    }

#pragma unroll
    for (int mi = 0; mi < 2; mi++)
#pragma unroll
        for (int r = 0; r < 4; r++) {
            const int row = bm + wm + mi * 16 + quad * 4 + r;
#pragma unroll
            for (int ni = 0; ni < 2; ni++) {
                const int col = bn + wn + ni * 16 + li;
                float v = acc[mi][ni][r];
                if (bias) v += ldx(bias, col, isb);
                if (res)  v += ldx(res, (size_t)row * N + col, res_ext ? isb : true);
                stx(C, (size_t)row * N + col, c_ext ? isb : true, v);
            }
        }
}

// ---------------------------------------------------------------------------
// Slow-path MFMA GEMM (round-7 verified, used only if workspace is small).
// ---------------------------------------------------------------------------
__global__ __launch_bounds__(256) void gemm_mfma(
    const bf16* __restrict__ A, long a_bs, const void* __restrict__ W,
    void* __restrict__ C, size_t c_off, long c_bs, int c_ext,
    const void* __restrict__ bias,
    const void* __restrict__ res, size_t res_off, long res_bs, int res_ext,
    int K, int N, int mode, int R,
    bf16* __restrict__ kb0, bf16* __restrict__ kb1,
    const int* __restrict__ flagp) {

    const bool isb = (*flagp != 0);
    const bool resb = res_ext ? isb : true;
    const bool cb = c_ext ? isb : true;
    const int z = blockIdx.z;

    const bf16* Az = A + (size_t)z * a_bs;
    const size_t coz = c_off + (size_t)z * c_bs;
    const size_t roz = res_off + (size_t)z * res_bs;

    __shared__ bf16 As[64][72];
    __shared__ bf16 Bs[64][72];

    const int t = threadIdx.x;
    const int w = t >> 6, lane = t & 63, li = lane & 15, quad = lane >> 4;
    const int wm = (w & 1) * 32, wn = (w >> 1) * 32;
    const int bm = blockIdx.y * 64, bn = blockIdx.x * 64;

    f32x4 acc[2][2];
#pragma unroll
    for (int mi = 0; mi < 2; mi++)
#pragma unroll
        for (int ni = 0; ni < 2; ni++)
#pragma unroll
            for (int r = 0; r < 4; r++) acc[mi][ni][r] = 0.f;

    for (int k0 = 0; k0 < K; k0 += 64) {
#pragma unroll
        for (int c = 0; c < 2; c++) {
            const int lin = t * 16 + c * 8;
            const int row = lin >> 6, kk = lin & 63;
            *(bf16x8*)&As[row][kk] = *(const bf16x8*)(Az + (size_t)(bm + row) * K + k0 + kk);
        }
#pragma unroll
        for (int c = 0; c < 2; c++) {
            const int lin = t * 16 + c * 8;
            const int kk = lin >> 6, n0 = lin & 63;
            float v[8];
            ldx8(W, (size_t)(k0 + kk) * N + bn + n0, isb, v);
            const int st = t & 7;
#pragma unroll
            for (int i = 0; i < 8; i++) {
                const int ii = (i + st) & 7;
                Bs[n0 + ii][kk] = f2b(v[ii]);
            }
        }
        __syncthreads();
#pragma unroll
        for (int kc = 0; kc < 2; kc++) {
            bf16x8 af[2], bfr[2];
#pragma unroll
            for (int mi = 0; mi < 2; mi++)
                af[mi] = *(const bf16x8*)&As[wm + mi * 16 + li][kc * 32 + quad * 8];
#pragma unroll
            for (int ni = 0; ni < 2; ni++)
                bfr[ni] = *(const bf16x8*)&Bs[wn + ni * 16 + li][kc * 32 + quad * 8];
#pragma unroll
            for (int mi = 0; mi < 2; mi++)
#pragma unroll
                for (int ni = 0; ni < 2; ni++)
                    acc[mi][ni] = __builtin_amdgcn_mfma_f32_16x16x32_bf16(
                        af[mi], bfr[ni], acc[mi][ni], 0, 0, 0);
        }
        __syncthreads();
    }

    if (mode == 1) {
        bf16* kb = z ? kb1 : kb0;
#pragma unroll
        for (int mi = 0; mi < 2; mi++)
#pragma unroll
            for (int r = 0; r < 4; r++) {
                const int row = bm + wm + mi * 16 + quad * 4 + r;
#pragma unroll
                for (int ni = 0; ni < 2; ni++) {
                    const int col = bn + wn + ni * 16 + li;
                    const float v = acc[mi][ni][r];
                    if (col < 1024)
                        kb[(size_t)row * 1024 + col] = f2b(v);
                    else
                        kb[(size_t)1024 * R + (size_t)(col - 1024) * R + row] = f2b(v);
                }
            }
        return;
    }

#pragma unroll
    for (int mi = 0; mi < 2; mi++)
#pragma unroll
        for (int r = 0; r < 4; r++) {
            const int row = bm + wm + mi * 16 + quad * 4 + r;
#pragma unroll
            for (int ni = 0; ni < 2; ni++) {
                const int col = bn + wn + ni * 16 + li;
                float v = acc[mi][ni][r];
                if (bias) v += ldx(bias, col, isb);
                if (res)  v += ldx(res, roz + (size_t)row * N + col, resb);
                stx(C, coz + (size_t)row * N + col, cb, v);
            }
        }
}

// ---------------------------------------------------------------------------
// attn_flash: round-0 verified body — best measured (134.6 µs SA). Five
// variants failed; frozen. (Codegen lottery across builds: ±5 µs.)
// ---------------------------------------------------------------------------
__global__ __launch_bounds__(64) void attn_flash(
    const bf16* __restrict__ qb, const bf16* __restrict__ kv0,
    const bf16* __restrict__ kv1,
    const void* __restrict__ rel_emb, bf16* __restrict__ out,
    long qo_bs, long out_bs, int m, int rel_off, const int* __restrict__ flagp) {

    const float SC = 0.125f * 1.44269504f;
    const bool isb = (*flagp != 0);
    const int id = blockIdx.x;
    const int xcd = id & 7;
    const int slot = id >> 3;
    const int c = (slot >> 6) * 8 + xcd;
    const int h = c & 15, z = c >> 4;
    const int q0 = (slot & 63) * 32;
    const int t = threadIdx.x;
    const int li = t & 15, quad = t >> 4;

    const bf16* qz = qb + (size_t)z * qo_bs;
    bf16* oz = out + (size_t)z * out_bs;
    const bf16* kb = z ? kv1 : kv0;
    const bf16* vtb = kb + (size_t)m * 1024;

    __shared__ float bias_s[32];
    __shared__ float tab[2080];
    __shared__ bf16 Ps[16][40];

    if (t < 32) bias_s[t] = ldx(rel_emb, t * 16 + h, isb) * SC - 40.0f;
    __syncthreads();

    const int tsz = m + 31;
    for (int i = t; i < tsz; i += 64) {
        const int rel = i - 31 - q0 + rel_off;
        const int ab = rel < 0 ? -rel : rel;
        int bucket = rel >= 0 ? 16 : 0;
        if (ab < 8) {
            bucket += ab;
        } else {
            const int p = 31 - __clz(ab);
            const int k2 = 2 * p + ((ab * ab >= (1 << (2 * p + 1))) ? 1 : 0);
            const int val = k2 + 2;
            bucket += (val > 15) ? 15 : val;
        }
        tab[i] = bias_s[bucket];
    }
    __syncthreads();

    bf16x8 aq[2][2];
#pragma unroll
    for (int g = 0; g < 2; g++)
#pragma unroll
        for (int kc = 0; kc < 2; kc++)
            aq[g][kc] = *(const bf16x8*)(qz + (size_t)(q0 + g * 16 + li) * 1024
                                         + h * 64 + kc * 32 + quad * 8);

    bf16x8 ones;
#pragma unroll
    for (int j = 0; j < 8; j++) ((short*)&ones)[j] = 0x3F80;

    f32x4 o[2][4], lac[2];
#pragma unroll
    for (int g = 0; g < 2; g++) {
#pragma unroll
        for (int r = 0; r < 4; r++) lac[g][r] = 0.f;
#pragma unroll
        for (int nb = 0; nb < 4; nb++)
#pragma unroll
            for (int r = 0; r < 4; r++) o[g][nb][r] = 0.f;
    }

    for (int j0 = 0; j0 < m; j0 += 32) {
        bf16x8 kf[4], vf[4];
#pragma unroll
        for (int nb = 0; nb < 2; nb++)
#pragma unroll
            for (int kc = 0; kc < 2; kc++)
                kf[nb * 2 + kc] = *(const bf16x8*)(
                    kb + (size_t)(j0 + nb * 16 + li) * 1024 + h * 64 + kc * 32 + quad * 8);
#pragma unroll
        for (int nb = 0; nb < 4; nb++)
            vf[nb] = *(const bf16x8*)(
                vtb + (size_t)(h * 64 + nb * 16 + li) * m + j0 + quad * 8);

#pragma unroll
        for (int g = 0; g < 2; g++) {
            f32x4 s[2];
            __builtin_amdgcn_s_setprio(1);
#pragma unroll
            for (int nb = 0; nb < 2; nb++) {
                f32x4 a;
#pragma unroll
                for (int r = 0; r < 4; r++) a[r] = 0.f;
#pragma unroll
                for (int kc = 0; kc < 2; kc++)
                    a = __builtin_amdgcn_mfma_f32_16x16x32_bf16(aq[g][kc], kf[nb * 2 + kc],
                                                                a, 0, 0, 0);
                s[nb] = a;
            }
            __builtin_amdgcn_s_setprio(0);
#pragma unroll
            for (int nb = 0; nb < 2; nb++)
#pragma unroll
                for (int r = 0; r < 4; r++) {
                    const int ti = j0 + nb * 16 + li + 31 - (g * 16 + quad * 4 + r);
                    s[nb][r] = exp2f(fmaf(s[nb][r], SC, tab[ti]));
                }
#pragma unroll
            for (int nb = 0; nb < 2; nb++)
#pragma unroll
                for (int r = 0; r < 4; r++)
                    Ps[quad * 4 + r][nb * 16 + li] = f2b(s[nb][r]);
            const bf16x8 ap = *(const bf16x8*)&Ps[li][quad * 8];
            __builtin_amdgcn_s_setprio(1);
#pragma unroll
            for (int nb = 0; nb < 4; nb++)
                o[g][nb] = __builtin_amdgcn_mfma_f32_16x16x32_bf16(ap, vf[nb],
                                                                   o[g][nb], 0, 0, 0);
            lac[g] = __builtin_amdgcn_mfma_f32_16x16x32_bf16(ap, ones, lac[g], 0, 0, 0);
            __builtin_amdgcn_s_setprio(0);
        }
    }

#pragma unroll
    for (int g = 0; g < 2; g++)
#pragma unroll
        for (int r = 0; r < 4; r++) {
            const float inv = 1.0f / lac[g][r];
            const int qi = q0 + g * 16 + quad * 4 + r;
#pragma unroll
            for (int nb = 0; nb < 4; nb++)
                oz[(size_t)qi * 1024 + h * 64 + nb * 16 + li] = f2b(o[g][nb][r] * inv);
        }
}

// ---------------------------------------------------------------------------
// Launcher. Fast path (ws >= 56 MB + 256; measured ws = 256 MB):
//   F_A|F_B|F_C (24 MB) + WT (8) + F_X (8) + F_Y (6) + WT2 (8) = 54 MB.
// Round-12 schedule (best: 459.1 µs) with wconv + both LNs merged into ONE
// prologue dispatch. Fallback: round-7 plan (24 MB).
// ---------------------------------------------------------------------------
extern "C" void kernel_launch(void* const* d_in, const int* in_sizes, int n_in,
                              void* d_out, int out_size, void* d_ws, size_t ws_size,
                              hipStream_t stream) {
    const long M1 = 1024 * 1024;
    const long M2 = 2 * 1024 * 1024;
    const long M4 = 4 * 1024 * 1024;
    if (ws_size < 24u * 1024 * 1024 + 256) return;

    const void* x      = d_in[0];
    const void* ctx    = d_in[1];
    const void* sa_ng  = d_in[2];
    const void* sa_nb  = d_in[3];
    const void* sa_ncg = d_in[4];
    const void* sa_ncb = d_in[5];
    const void* sa_wq  = d_in[6];
    const void* sa_wkv = d_in[7];
    const void* sa_wo  = d_in[8];
    const void* sa_bo  = d_in[9];
    const void* sa_rel = d_in[10];
    const void* ca_ng  = d_in[11];
    const void* ca_nb  = d_in[12];
    const void* ca_ncg = d_in[13];
    const void* ca_ncb = d_in[14];
    const void* ca_wq  = d_in[15];
    const void* ca_wkv = d_in[16];
    const void* ca_wo  = d_in[17];
    const void* ca_bo  = d_in[18];
    const void* ca_rel = d_in[19];

    int* flag = (int*)d_ws;
    bf16* F_A = (bf16*)((char*)d_ws + 256);
    bf16* F_B = F_A + M4;
    bf16* F_C = F_B + M4;
    bf16* WT  = F_C + M4;                // fast path only (SA weights)
    bf16* F_X = WT + M4;                 // fast path only (xn buffer)
    bf16* F_Y = F_X + M4;                // fast path only (ctx-LN + CA K/V)
    bf16* WT2 = F_Y + 3 * M1;            // fast path only (CA weights)
    bf16* qd  = (bf16*)d_out;            // d_out as bf16 scratch (q / ao)

    sniff_kernel<<<1, 256, 0, stream>>>(x, flag);

    if (ws_size >= 56u * 1024 * 1024 + 256) {
        bf16* WTq  = WT;                 // [1024][1024]
        bf16* WTkv = WT + M1;            // [2048][1024]
        bf16* WTo  = WT + 3 * M1;        // [1024][1024]
        bf16* WT2q  = WT2;
        bf16* WT2kv = WT2 + M1;
        bf16* WT2o  = WT2 + 3 * M1;
        bf16* CAK0 = F_Y + M1;           // z0: K[512][1024] + V^T[1024][512]
        bf16* CAK1 = F_Y + 2 * M1;       // z1: same layout

        // ===== prologue: weight transposes + both input LNs (ONE dispatch)
        prologue_kernel<<<dim3(7168), 256, 0, stream>>>(
            sa_wq, sa_wkv, sa_wo, ca_wq, ca_wkv, ca_wo,
            WTq, WTkv, WTo, WT2q, WT2kv, WT2o,
            x, ctx, sa_ng, sa_nb, sa_ncg, sa_ncb, ca_ncg, ca_ncb,
            F_X, F_B, F_Y, flag);

        // ===== BIG (128^2): SA-q + SA-kv + CA-kv =====
        {
            GArgs gq = {};
            gq.A = F_X; gq.Bt = WTq; gq.C = qd;
            gq.N = 1024; gq.nbx = 8; gq.nby = 32;
            GArgs gkv = {};
            gkv.A = F_B; gkv.Bt = WTkv;
            gkv.N = 2048; gkv.mode = 1; gkv.zsplit = 2048; gkv.zrows = 2048;
            gkv.kb0 = F_A; gkv.kb1 = F_C; gkv.nbx = 16; gkv.nby = 32;
            GArgs gca = {};
            gca.A = F_Y; gca.Bt = WT2kv;
            gca.N = 2048; gca.mode = 1; gca.zsplit = 512; gca.zrows = 512;
            gca.kb0 = CAK0; gca.kb1 = CAK1; gca.nbx = 16; gca.nby = 8;
            gemm_fused<<<dim3(40, 32), 256, 0, stream>>>(gq, gkv, gca, flag);
        }

        // ===== self-attention + o-proj =====
        attn_flash<<<dim3(2048), 64, 0, stream>>>(
            qd, F_A, F_C, sa_rel, qd, M2, M2, 2048, 0, flag);
        gemm_t64<<<dim3(16, 64), 256, 0, stream>>>(
            qd, WTo, F_B, 0, sa_bo, x, 1, 1024, flag);

        // ===== cross-attention =====
        ln_dual_kernel<<<dim3(2048, 1, 2), 256, 0, stream>>>(
            F_B, 0, M2, 0, ca_ng, ca_nb, nullptr, nullptr, F_X, nullptr, M2, flag);
        gemm_t64<<<dim3(16, 64), 256, 0, stream>>>(
            F_X, WT2q, qd, 0, nullptr, nullptr, 0, 1024, flag);
        attn_flash<<<dim3(2048), 64, 0, stream>>>(
            qd, CAK0, CAK1, ca_rel, F_C, M2, M2, 512, 1536, flag);
        gemm_t64<<<dim3(16, 64), 256, 0, stream>>>(
            F_C, WT2o, d_out, 1, ca_bo, F_B, 0, 1024, flag);
        return;
    }

    // ================= fallback: round-7 verified plan =================
    ln_dual_kernel<<<dim3(2048, 1, 2), 256, 0, stream>>>(
        x, 0, M2, 1, sa_ng, sa_nb, sa_ncg, sa_ncb, F_A, F_B, M2, flag);
    gemm_mfma<<<dim3(16, 32, 2), 256, 0, stream>>>(
        F_A, M2, sa_wq, qd, 0, M2, 0, nullptr, nullptr, 0, 0, 0,
        1024, 1024, 0, 0, nullptr, nullptr, flag);
    gemm_mfma<<<dim3(32, 32, 2), 256, 0, stream>>>(
        F_B, M2, sa_wkv, nullptr, 0, 0, 0, nullptr, nullptr, 0, 0, 0,
        1024, 2048, 1, 2048, F_A, F_C, flag);
    attn_flash<<<dim3(2048), 64, 0, stream>>>(
        qd, F_A, F_C, sa_rel, qd, M2, M2, 2048, 0, flag);
    gemm_mfma<<<dim3(16, 32, 2), 256, 0, stream>>>(
        qd, M2, sa_wo, F_B, 0, M2, 0, sa_bo, x, 0, M2, 1,
        1024, 1024, 0, 0, nullptr, nullptr, flag);

    ln_dual_kernel<<<dim3(2048, 1, 2), 256, 0, stream>>>(
        F_B, 0, M2, 0, ca_ng, ca_nb, nullptr, nullptr, F_A, nullptr, M2, flag);
    ln_dual_kernel<<<dim3(512, 1, 2), 256, 0, stream>>>(
        ctx, 0, 512 * 1024, 1, ca_ncg, ca_ncb, nullptr, nullptr,
        F_C, nullptr, 512 * 1024, flag);
    gemm_mfma<<<dim3(16, 32, 2), 256, 0, stream>>>(
        F_A, M2, ca_wq, qd, 0, M2, 0, nullptr, nullptr, 0, 0, 0,
        1024, 1024, 0, 0, nullptr, nullptr, flag);
    gemm_mfma<<<dim3(32, 8, 2), 256, 0, stream>>>(
        F_C, 512 * 1024, ca_wkv, nullptr, 0, 0, 0, nullptr, nullptr, 0, 0, 0,
        1024, 2048, 1, 512, F_A, F_A + M1, flag);
    attn_flash<<<dim3(2048), 64, 0, stream>>>(
        qd, F_A, F_A + M1, ca_rel, F_C, M2, M2, 512, 1536, flag);
    gemm_mfma<<<dim3(16, 32, 2), 256, 0, stream>>>(
        F_C, M2, ca_wo, d_out, 0, M2, 1, ca_bo, F_B, 0, M2, 0,
        1024, 1024, 0, 0, nullptr, nullptr, flag);
}

// Round 14
// 448.012 us; speedup vs baseline: 1.0536x; 1.0169x over previous
//
#include <hip/hip_runtime.h>
#include <hip/hip_bf16.h>

typedef __hip_bfloat16 bf16;
typedef __attribute__((ext_vector_type(8))) short bf16x8;   // 8 bf16 (4 VGPRs)
typedef __attribute__((ext_vector_type(4))) float f32x4;    // MFMA accum

__device__ __forceinline__ float b2f(bf16 v) { return __bfloat162float(v); }
__device__ __forceinline__ bf16 f2b(float v) { return __float2bfloat16(v); }

// Scalar load/store from an external buffer whose dtype is decided by isb.
__device__ __forceinline__ float ldx(const void* p, size_t i, bool isb) {
    return isb ? b2f(((const bf16*)p)[i]) : ((const float*)p)[i];
}
__device__ __forceinline__ void stx(void* p, size_t i, bool isb, float v) {
    if (isb) ((bf16*)p)[i] = f2b(v);
    else     ((float*)p)[i] = v;
}
// Vector (8-elem) external load; i must be a multiple of 8.
__device__ __forceinline__ void ldx8(const void* p, size_t i, bool isb, float* o) {
    if (isb) {
        const bf16x8 v = *(const bf16x8*)((const bf16*)p + i);
#pragma unroll
        for (int j = 0; j < 8; j++) o[j] = b2f(((const bf16*)&v)[j]);
    } else {
        const float4 v0 = *(const float4*)((const float*)p + i);
        const float4 v1 = *(const float4*)((const float*)p + i + 4);
        o[0]=v0.x; o[1]=v0.y; o[2]=v0.z; o[3]=v0.w;
        o[4]=v1.x; o[5]=v1.y; o[6]=v1.z; o[7]=v1.w;
    }
}

// ---------------------------------------------------------------------------
// Dtype sniffer (verified round 3): decides fp32 vs bf16 external data.
// ---------------------------------------------------------------------------
__global__ void sniff_kernel(const void* __restrict__ x, int* __restrict__ flag) {
    const unsigned* w = (const unsigned*)x;
    const int t = threadIdx.x;
    int cnt = 0;
#pragma unroll
    for (int i = 0; i < 4; i++) {
        const unsigned word = w[t * 4 + i];
        const int e = (word >> 23) & 0xFF;
        cnt += (e >= 192) ? 1 : 0;
    }
    __shared__ int red[4];
#pragma unroll
    for (int o = 32; o > 0; o >>= 1) cnt += __shfl_down(cnt, o);
    if ((t & 63) == 0) red[t >> 6] = cnt;
    __syncthreads();
    if (t == 0) flag[0] = ((red[0] + red[1] + red[2] + red[3]) >= 512) ? 1 : 0;
}

// ---------------------------------------------------------------------------
// Merged PROLOGUE kernel (round-13 verified WIN): weight transposes (both
// phases) AND both input LNs in ONE dispatch. Block-uniform demux.
// ---------------------------------------------------------------------------
__global__ void prologue_kernel(
    const void* __restrict__ Wq,  const void* __restrict__ Wkv,
    const void* __restrict__ Wo,  const void* __restrict__ Wq2,
    const void* __restrict__ Wkv2, const void* __restrict__ Wo2,
    bf16* __restrict__ WTq,  bf16* __restrict__ WTkv,  bf16* __restrict__ WTo,
    bf16* __restrict__ WTq2, bf16* __restrict__ WTkv2, bf16* __restrict__ WTo2,
    const void* __restrict__ x, const void* __restrict__ ctx,
    const void* __restrict__ g1, const void* __restrict__ b1,
    const void* __restrict__ g2, const void* __restrict__ b2,
    const void* __restrict__ g3, const void* __restrict__ b3,
    bf16* __restrict__ outX, bf16* __restrict__ outB, bf16* __restrict__ outY,
    const int* __restrict__ flagp) {

    const bool isb = (*flagp != 0);
    const int bid = blockIdx.x;
    const int t = threadIdx.x;

    __shared__ __align__(16) char smem[16640];   // 64*65*4 = 16640 B

    if (bid < 2048) {
        // ================= wconv path (verified wconv8 body) =============
        float (*T)[65] = (float(*)[65])smem;
        const int bx = bid & 15, by = (bid >> 4) & 15, z = bid >> 8;
        const int zz = z & 3;
        const bool ca = z >= 4;
        const void* W = ca ? ((zz == 0) ? Wq2 : (zz == 3) ? Wo2 : Wkv2)
                           : ((zz == 0) ? Wq  : (zz == 3) ? Wo  : Wkv);
        bf16* Wt      = ca ? ((zz == 0) ? WTq2 : (zz == 3) ? WTo2 : WTkv2)
                           : ((zz == 0) ? WTq  : (zz == 3) ? WTo  : WTkv);
        const int N   = (zz == 1 || zz == 2) ? 2048 : 1024;
        const int K = 1024;
        const int n0 = bx * 64 + ((zz == 2) ? 1024 : 0);
        const int k0 = by * 64;
        const int rr = t >> 3, c8 = (t & 7) * 8;
#pragma unroll
        for (int i = 0; i < 2; i++) {
            const int row = rr + i * 32;
            float v[8];
            ldx8(W, (size_t)(k0 + row) * N + n0 + c8, isb, v);
#pragma unroll
            for (int j = 0; j < 8; j++) T[row][c8 + j] = v[j];
        }
        __syncthreads();
#pragma unroll
        for (int i = 0; i < 2; i++) {
            const int row = rr + i * 32;   // n-index within tile
            bf16x8 ov;
#pragma unroll
            for (int j = 0; j < 8; j++) ((bf16*)&ov)[j] = f2b(T[c8 + j][row]);
            *(bf16x8*)(Wt + (size_t)(n0 + row) * K + k0 + c8) = ov;
        }
        return;
    }

    // =================== LN path (verified ln_pro body) ==================
    const int F = 1024;
    float* red1 = (float*)smem;
    float* red2 = (float*)smem + 4;
    const int lnid = bid - 2048;             // 0..5119
    const int z = (lnid >= 2560) ? 1 : 0;
    const int bid2 = lnid - z * 2560;        // 0..2559
    const bool isCtx = bid2 >= 2048;
    const int row = isCtx ? bid2 - 2048 : bid2;
    const void* in = isCtx ? ctx : x;
    const size_t base = (isCtx ? (size_t)z * (512 * 1024)
                               : (size_t)z * (2048 * 1024)) + (size_t)row * F;

    float v[4];
    float s = 0.f;
#pragma unroll
    for (int i = 0; i < 4; i++) { v[i] = ldx(in, base + t + 256 * i, isb); s += v[i]; }

#pragma unroll
    for (int o = 32; o > 0; o >>= 1) s += __shfl_down(s, o);
    if ((t & 63) == 0) red1[t >> 6] = s;
    __syncthreads();
    const float mean = (red1[0] + red1[1] + red1[2] + red1[3]) * (1.0f / F);

    float ss = 0.f;
#pragma unroll
    for (int i = 0; i < 4; i++) { float d = v[i] - mean; ss += d * d; }
#pragma unroll
    for (int o = 32; o > 0; o >>= 1) ss += __shfl_down(ss, o);
    if ((t & 63) == 0) red2[t >> 6] = ss;
    __syncthreads();
    const float var = (red2[0] + red2[1] + red2[2] + red2[3]) * (1.0f / F);
    const float rn = rsqrtf(var + 1e-5f);

    if (isCtx) {
        const size_t obase = (size_t)z * (512 * 1024) + (size_t)row * F;
#pragma unroll
        for (int i = 0; i < 4; i++) {
            const int idx = t + 256 * i;
            const float nv = (v[i] - mean) * rn;
            outY[obase + idx] = f2b(nv * ldx(g3, idx, isb) + ldx(b3, idx, isb));
        }
    } else {
        const size_t obase = (size_t)z * (2048 * 1024) + (size_t)row * F;
#pragma unroll
        for (int i = 0; i < 4; i++) {
            const int idx = t + 256 * i;
            const float nv = (v[i] - mean) * rn;
            outX[obase + idx] = f2b(nv * ldx(g1, idx, isb) + ldx(b1, idx, isb));
            outB[obase + idx] = f2b(nv * ldx(g2, idx, isb) + ldx(b2, idx, isb));
        }
    }
}

// ---------------------------------------------------------------------------
// LayerNorm over F=1024, batch-fused via grid.z (per-batch strides in elems).
// Used for the mid-pipeline CA-x LN (and the fallback path).
// ---------------------------------------------------------------------------
__global__ void ln_dual_kernel(const void* __restrict__ in, size_t in_off, long in_bs,
                               int in_ext,
                               const void* __restrict__ g1, const void* __restrict__ b1,
                               const void* __restrict__ g2, const void* __restrict__ b2,
                               bf16* __restrict__ out1, bf16* __restrict__ out2,
                               long out_bs, const int* __restrict__ flagp) {
    const int F = 1024;
    const bool isb = (*flagp != 0);
    const bool inb = in_ext ? isb : true;
    const int row = blockIdx.x;
    const int z = blockIdx.z;
    const int t = threadIdx.x;
    const size_t base = in_off + (size_t)z * in_bs + (size_t)row * F;
    const size_t obase = (size_t)z * out_bs + (size_t)row * F;

    float v[4];
    float s = 0.f;
#pragma unroll
    for (int i = 0; i < 4; i++) { v[i] = ldx(in, base + t + 256 * i, inb); s += v[i]; }

    __shared__ float red1[4];
    __shared__ float red2[4];
#pragma unroll
    for (int o = 32; o > 0; o >>= 1) s += __shfl_down(s, o);
    if ((t & 63) == 0) red1[t >> 6] = s;
    __syncthreads();
    const float mean = (red1[0] + red1[1] + red1[2] + red1[3]) * (1.0f / F);

    float ss = 0.f;
#pragma unroll
    for (int i = 0; i < 4; i++) { float d = v[i] - mean; ss += d * d; }
#pragma unroll
    for (int o = 32; o > 0; o >>= 1) ss += __shfl_down(ss, o);
    if ((t & 63) == 0) red2[t >> 6] = ss;
    __syncthreads();
    const float var = (red2[0] + red2[1] + red2[2] + red2[3]) * (1.0f / F);
    const float rn = rsqrtf(var + 1e-5f);

#pragma unroll
    for (int i = 0; i < 4; i++) {
        const int idx = t + 256 * i;
        const float nv = (v[i] - mean) * rn;
        out1[obase + idx] = f2b(nv * ldx(g1, idx, isb) + ldx(b1, idx, isb));
        if (out2) out2[obase + idx] = f2b(nv * ldx(g2, idx, isb) + ldx(b2, idx, isb));
    }
}

// ---------------------------------------------------------------------------
// Grouped GEMM args. C = A[R,1024] @ Bt^T, 128x128 tile, BK=64, 4 waves.
// ---------------------------------------------------------------------------
struct GArgs {
    const bf16* A; const bf16* Bt; void* C;
    const void* bias; const void* res;
    bf16* kb0; bf16* kb1;
    int c_ext, res_ext, N, mode, zsplit, zrows, nbx, nby;
};

// ---------------------------------------------------------------------------
// Reg-staged grouped GEMM (verified body, padded LDS). Mode-1 V-half writes
// V^T via LDS transpose (round-8 win). Used for the BIG 3-slot dispatch at
// 128^2 tiles / 3.5 blocks/CU — round 11 proved 64^2 tiles REGRESS here.
// ---------------------------------------------------------------------------
__global__ __launch_bounds__(256) void gemm_fused(GArgs ga, GArgs gb, GArgs gc,
                                                  const int* __restrict__ flagp) {
    int bx = (int)blockIdx.x;
    GArgs g;
    if (bx < ga.nbx) { g = ga; }
    else if (bx < ga.nbx + gb.nbx) { g = gb; bx -= ga.nbx; }
    else { g = gc; bx -= ga.nbx + gb.nbx; }
    const int by = (int)blockIdx.y;
    if (by >= g.nby) return;               // block-uniform: no divergent barrier

    const int K = 1024;
    const bool isb = (*flagp != 0);

    __shared__ bf16 As[128][72];
    __shared__ bf16 Bs[128][72];

    const int t = threadIdx.x;
    const int w = t >> 6, lane = t & 63, li = lane & 15, quad = lane >> 4;
    const int wm = (w & 1) * 64, wn = (w >> 1) * 64;
    const int bm = by * 128, bn = bx * 128;

    f32x4 acc[4][4];
#pragma unroll
    for (int mi = 0; mi < 4; mi++)
#pragma unroll
        for (int ni = 0; ni < 4; ni++)
#pragma unroll
            for (int r = 0; r < 4; r++) acc[mi][ni][r] = 0.f;

    for (int k0 = 0; k0 < K; k0 += 64) {
#pragma unroll
        for (int c = 0; c < 4; c++) {
            const int d = c * 256 + t;
            const int row = d >> 3, ch = (d & 7) * 8;
            *(bf16x8*)&As[row][ch] = *(const bf16x8*)(g.A + (size_t)(bm + row) * K + k0 + ch);
            *(bf16x8*)&Bs[row][ch] = *(const bf16x8*)(g.Bt + (size_t)(bn + row) * K + k0 + ch);
        }
        __syncthreads();
#pragma unroll
        for (int kc = 0; kc < 2; kc++) {
            bf16x8 af[4], bfr[4];
#pragma unroll
            for (int i = 0; i < 4; i++) {
                af[i]  = *(const bf16x8*)&As[wm + i * 16 + li][kc * 32 + quad * 8];
                bfr[i] = *(const bf16x8*)&Bs[wn + i * 16 + li][kc * 32 + quad * 8];
            }
#pragma unroll
            for (int mi = 0; mi < 4; mi++)
#pragma unroll
                for (int ni = 0; ni < 4; ni++)
                    acc[mi][ni] = __builtin_amdgcn_mfma_f32_16x16x32_bf16(
                        af[mi], bfr[ni], acc[mi][ni], 0, 0, 0);
        }
        __syncthreads();
    }

    if (g.mode == 1) {
        if (bn >= 1024) {
            // -------- V block: LDS-transposed coalesced V^T store --------
            const int batch = (bm < g.zsplit) ? 0 : 1;
            bf16* kb = batch ? g.kb1 : g.kb0;
            const int brow = bm - batch * g.zsplit;
            const int vc0 = bn - 1024;
            bf16 (*T)[136] = (bf16(*)[136])&As[0][0];   // 64x136 fits in As
            const int c = t >> 2, seg = t & 3;           // c: V^T row, seg: 64B
#pragma unroll
            for (int p = 0; p < 2; p++) {
                if ((w >> 1) == p) {                     // waves owning cols p*64..
#pragma unroll
                    for (int mi = 0; mi < 4; mi++)
#pragma unroll
                        for (int ni = 0; ni < 4; ni++)
#pragma unroll
                            for (int r = 0; r < 4; r++)
                                T[ni * 16 + li][wm + mi * 16 + quad * 4 + r] =
                                    f2b(acc[mi][ni][r]);
                }
                __syncthreads();
                bf16* dst = kb + (size_t)1024 * g.zrows
                            + (size_t)(vc0 + p * 64 + c) * g.zrows + brow + seg * 32;
#pragma unroll
                for (int j = 0; j < 4; j++)
                    *(bf16x8*)(dst + j * 8) = *(const bf16x8*)&T[c][seg * 32 + j * 8];
                __syncthreads();
            }
            return;
        }
        // -------- K block: verified coalesced row-major store --------
#pragma unroll
        for (int mi = 0; mi < 4; mi++)
#pragma unroll
            for (int r = 0; r < 4; r++) {
                const int row = bm + wm + mi * 16 + quad * 4 + r;
                bf16* kb = (row < g.zsplit) ? g.kb0 : g.kb1;
                const int lrow = (row < g.zsplit) ? row : row - g.zsplit;
#pragma unroll
                for (int ni = 0; ni < 4; ni++) {
                    const int col = bn + wn + ni * 16 + li;
                    kb[(size_t)lrow * 1024 + col] = f2b(acc[mi][ni][r]);
                }
            }
        return;
    }

#pragma unroll
    for (int mi = 0; mi < 4; mi++)
#pragma unroll
        for (int r = 0; r < 4; r++) {
            const int row = bm + wm + mi * 16 + quad * 4 + r;
#pragma unroll
            for (int ni = 0; ni < 4; ni++) {
                const int col = bn + wn + ni * 16 + li;
                float v = acc[mi][ni][r];
                if (g.bias) v += ldx(g.bias, col, isb);
                if (g.res)  v += ldx(g.res, (size_t)row * g.N + col, g.res_ext ? isb : true);
                stx(g.C, (size_t)row * g.N + col, g.c_ext ? isb : true, v);
            }
        }
}

// ---------------------------------------------------------------------------
// Round-10 verified: 64x64-tile mode-0 GEMM for the three standalone GEMMs
// (SA-oproj, CA-q, CA-oproj), grid (16,64) = 4 blocks/CU. WIN: −21.6 µs.
// ---------------------------------------------------------------------------
__global__ __launch_bounds__(256) void gemm_t64(
    const bf16* __restrict__ A, const bf16* __restrict__ Bt,
    void* __restrict__ C, int c_ext,
    const void* __restrict__ bias,
    const void* __restrict__ res, int res_ext, int N,
    const int* __restrict__ flagp) {

    const int K = 1024;
    const bool isb = (*flagp != 0);

    __shared__ bf16 As[64][72];
    __shared__ bf16 Bs[64][72];

    const int t = threadIdx.x;
    const int w = t >> 6, lane = t & 63, li = lane & 15, quad = lane >> 4;
    const int wm = (w & 1) * 32, wn = (w >> 1) * 32;
    const int bm = blockIdx.y * 64, bn = blockIdx.x * 64;

    f32x4 acc[2][2];
#pragma unroll
    for (int mi = 0; mi < 2; mi++)
#pragma unroll
        for (int ni = 0; ni < 2; ni++)
#pragma unroll
            for (int r = 0; r < 4; r++) acc[mi][ni][r] = 0.f;

    for (int k0 = 0; k0 < K; k0 += 64) {
#pragma unroll
        for (int c = 0; c < 2; c++) {
            const int d = c * 256 + t;
            const int row = d >> 3, ch = (d & 7) * 8;
            *(bf16x8*)&As[row][ch] = *(const bf16x8*)(A + (size_t)(bm + row) * K + k0 + ch);
            *(bf16x8*)&Bs[row][ch] = *(const bf16x8*)(Bt + (size_t)(bn + row) * K + k0 + ch);
        }
        __syncthreads();
#pragma unroll
        for (int kc = 0; kc < 2; kc++) {
            bf16x8 af[2], bfr[2];
#pragma unroll
            for (int mi = 0; mi < 2; mi++)
                af[mi] = *(const bf16x8*)&As[wm + mi * 16 + li][kc * 32 + quad * 8];
#pragma unroll
            for (int ni = 0; ni < 2; ni++)
                bfr[ni] = *(const bf16x8*)&Bs[wn + ni * 16 + li][kc * 32 + quad * 8];
#pragma unroll
            for (int mi = 0; mi < 2; mi++)
#pragma unroll
                for (int ni = 0; ni < 2; ni++)
                    acc[mi][ni] = __builtin_amdgcn_mfma_f32_16x16x32_bf16(
                        af[mi], bfr[ni], acc[mi][ni], 0, 0, 0);
        }
        __syncthreads();
    }

#pragma unroll
    for (int mi = 0; mi < 2; mi++)
#pragma unroll
        for (int r = 0; r < 4; r++) {
            const int row = bm + wm + mi * 16 + quad * 4 + r;
#pragma unroll
            for (int ni = 0; ni < 2; ni++) {
                const int col = bn + wn + ni * 16 + li;
                float v = acc[mi][ni][r];
                if (bias) v += ldx(bias, col, isb);
                if (res)  v += ldx(res, (size_t)row * N + col, res_ext ? isb : true);
                stx(C, (size_t)row * N + col, c_ext ? isb : true, v);
            }
        }
}

// ---------------------------------------------------------------------------
// Slow-path MFMA GEMM (round-7 verified, used only if workspace is small).
// ---------------------------------------------------------------------------
__global__ __launch_bounds__(256) void gemm_mfma(
    const bf16* __restrict__ A, long a_bs, const void* __restrict__ W,
    void* __restrict__ C, size_t c_off, long c_bs, int c_ext,
    const void* __restrict__ bias,
    const void* __restrict__ res, size_t res_off, long res_bs, int res_ext,
    int K, int N, int mode, int R,
    bf16* __restrict__ kb0, bf16* __restrict__ kb1,
    const int* __restrict__ flagp) {

    const bool isb = (*flagp != 0);
    const bool resb = res_ext ? isb : true;
    const bool cb = c_ext ? isb : true;
    const int z = blockIdx.z;

    const bf16* Az = A + (size_t)z * a_bs;
    const size_t coz = c_off + (size_t)z * c_bs;
    const size_t roz = res_off + (size_t)z * res_bs;

    __shared__ bf16 As[64][72];
    __shared__ bf16 Bs[64][72];

    const int t = threadIdx.x;
    const int w = t >> 6, lane = t & 63, li = lane & 15, quad = lane >> 4;
    const int wm = (w & 1) * 32, wn = (w >> 1) * 32;
    const int bm = blockIdx.y * 64, bn = blockIdx.x * 64;

    f32x4 acc[2][2];
#pragma unroll
    for (int mi = 0; mi < 2; mi++)
#pragma unroll
        for (int ni = 0; ni < 2; ni++)
#pragma unroll
            for (int r = 0; r < 4; r++) acc[mi][ni][r] = 0.f;

    for (int k0 = 0; k0 < K; k0 += 64) {
#pragma unroll
        for (int c = 0; c < 2; c++) {
            const int lin = t * 16 + c * 8;
            const int row = lin >> 6, kk = lin & 63;
            *(bf16x8*)&As[row][kk] = *(const bf16x8*)(Az + (size_t)(bm + row) * K + k0 + kk);
        }
#pragma unroll
        for (int c = 0; c < 2; c++) {
            const int lin = t * 16 + c * 8;
            const int kk = lin >> 6, n0 = lin & 63;
            float v[8];
            ldx8(W, (size_t)(k0 + kk) * N + bn + n0, isb, v);
            const int st = t & 7;
#pragma unroll
            for (int i = 0; i < 8; i++) {
                const int ii = (i + st) & 7;
                Bs[n0 + ii][kk] = f2b(v[ii]);
            }
        }
        __syncthreads();
#pragma unroll
        for (int kc = 0; kc < 2; kc++) {
            bf16x8 af[2], bfr[2];
#pragma unroll
            for (int mi = 0; mi < 2; mi++)
                af[mi] = *(const bf16x8*)&As[wm + mi * 16 + li][kc * 32 + quad * 8];
#pragma unroll
            for (int ni = 0; ni < 2; ni++)
                bfr[ni] = *(const bf16x8*)&Bs[wn + ni * 16 + li][kc * 32 + quad * 8];
#pragma unroll
            for (int mi = 0; mi < 2; mi++)
#pragma unroll
                for (int ni = 0; ni < 2; ni++)
                    acc[mi][ni] = __builtin_amdgcn_mfma_f32_16x16x32_bf16(
                        af[mi], bfr[ni], acc[mi][ni], 0, 0, 0);
        }
        __syncthreads();
    }

    if (mode == 1) {
        bf16* kb = z ? kb1 : kb0;
#pragma unroll
        for (int mi = 0; mi < 2; mi++)
#pragma unroll
            for (int r = 0; r < 4; r++) {
                const int row = bm + wm + mi * 16 + quad * 4 + r;
#pragma unroll
                for (int ni = 0; ni < 2; ni++) {
                    const int col = bn + wn + ni * 16 + li;
                    const float v = acc[mi][ni][r];
                    if (col < 1024)
                        kb[(size_t)row * 1024 + col] = f2b(v);
                    else
                        kb[(size_t)1024 * R + (size_t)(col - 1024) * R + row] = f2b(v);
                }
            }
        return;
    }

#pragma unroll
    for (int mi = 0; mi < 2; mi++)
#pragma unroll
        for (int r = 0; r < 4; r++) {
            const int row = bm + wm + mi * 16 + quad * 4 + r;
#pragma unroll
            for (int ni = 0; ni < 2; ni++) {
                const int col = bn + wn + ni * 16 + li;
                float v = acc[mi][ni][r];
                if (bias) v += ldx(bias, col, isb);
                if (res)  v += ldx(res, roz + (size_t)row * N + col, resb);
                stx(C, coz + (size_t)row * N + col, cb, v);
            }
        }
}

// ---------------------------------------------------------------------------
// attn_flash: round-0 verified 1-wave body. Used by the fallback path.
// ---------------------------------------------------------------------------
__global__ __launch_bounds__(64) void attn_flash(
    const bf16* __restrict__ qb, const bf16* __restrict__ kv0,
    const bf16* __restrict__ kv1,
    const void* __restrict__ rel_emb, bf16* __restrict__ out,
    long qo_bs, long out_bs, int m, int rel_off, const int* __restrict__ flagp) {

    const float SC = 0.125f * 1.44269504f;
    const bool isb = (*flagp != 0);
    const int id = blockIdx.x;
    const int xcd = id & 7;
    const int slot = id >> 3;
    const int c = (slot >> 6) * 8 + xcd;
    const int h = c & 15, z = c >> 4;
    const int q0 = (slot & 63) * 32;
    const int t = threadIdx.x;
    const int li = t & 15, quad = t >> 4;

    const bf16* qz = qb + (size_t)z * qo_bs;
    bf16* oz = out + (size_t)z * out_bs;
    const bf16* kb = z ? kv1 : kv0;
    const bf16* vtb = kb + (size_t)m * 1024;

    __shared__ float bias_s[32];
    __shared__ float tab[2080];
    __shared__ bf16 Ps[16][40];

    if (t < 32) bias_s[t] = ldx(rel_emb, t * 16 + h, isb) * SC - 40.0f;
    __syncthreads();

    const int tsz = m + 31;
    for (int i = t; i < tsz; i += 64) {
        const int rel = i - 31 - q0 + rel_off;
        const int ab = rel < 0 ? -rel : rel;
        int bucket = rel >= 0 ? 16 : 0;
        if (ab < 8) {
            bucket += ab;
        } else {
            const int p = 31 - __clz(ab);
            const int k2 = 2 * p + ((ab * ab >= (1 << (2 * p + 1))) ? 1 : 0);
            const int val = k2 + 2;
            bucket += (val > 15) ? 15 : val;
        }
        tab[i] = bias_s[bucket];
    }
    __syncthreads();

    bf16x8 aq[2][2];
#pragma unroll
    for (int g = 0; g < 2; g++)
#pragma unroll
        for (int kc = 0; kc < 2; kc++)
            aq[g][kc] = *(const bf16x8*)(qz + (size_t)(q0 + g * 16 + li) * 1024
                                         + h * 64 + kc * 32 + quad * 8);

    bf16x8 ones;
#pragma unroll
    for (int j = 0; j < 8; j++) ((short*)&ones)[j] = 0x3F80;

    f32x4 o[2][4], lac[2];
#pragma unroll
    for (int g = 0; g < 2; g++) {
#pragma unroll
        for (int r = 0; r < 4; r++) lac[g][r] = 0.f;
#pragma unroll
        for (int nb = 0; nb < 4; nb++)
#pragma unroll
            for (int r = 0; r < 4; r++) o[g][nb][r] = 0.f;
    }

    for (int j0 = 0; j0 < m; j0 += 32) {
        bf16x8 kf[4], vf[4];
#pragma unroll
        for (int nb = 0; nb < 2; nb++)
#pragma unroll
            for (int kc = 0; kc < 2; kc++)
                kf[nb * 2 + kc] = *(const bf16x8*)(
                    kb + (size_t)(j0 + nb * 16 + li) * 1024 + h * 64 + kc * 32 + quad * 8);
#pragma unroll
        for (int nb = 0; nb < 4; nb++)
            vf[nb] = *(const bf16x8*)(
                vtb + (size_t)(h * 64 + nb * 16 + li) * m + j0 + quad * 8);

#pragma unroll
        for (int g = 0; g < 2; g++) {
            f32x4 s[2];
            __builtin_amdgcn_s_setprio(1);
#pragma unroll
            for (int nb = 0; nb < 2; nb++) {
                f32x4 a;
#pragma unroll
                for (int r = 0; r < 4; r++) a[r] = 0.f;
#pragma unroll
                for (int kc = 0; kc < 2; kc++)
                    a = __builtin_amdgcn_mfma_f32_16x16x32_bf16(aq[g][kc], kf[nb * 2 + kc],
                                                                a, 0, 0, 0);
                s[nb] = a;
            }
            __builtin_amdgcn_s_setprio(0);
#pragma unroll
            for (int nb = 0; nb < 2; nb++)
#pragma unroll
                for (int r = 0; r < 4; r++) {
                    const int ti = j0 + nb * 16 + li + 31 - (g * 16 + quad * 4 + r);
                    s[nb][r] = exp2f(fmaf(s[nb][r], SC, tab[ti]));
                }
#pragma unroll
            for (int nb = 0; nb < 2; nb++)
#pragma unroll
                for (int r = 0; r < 4; r++)
                    Ps[quad * 4 + r][nb * 16 + li] = f2b(s[nb][r]);
            const bf16x8 ap = *(const bf16x8*)&Ps[li][quad * 8];
            __builtin_amdgcn_s_setprio(1);
#pragma unroll
            for (int nb = 0; nb < 4; nb++)
                o[g][nb] = __builtin_amdgcn_mfma_f32_16x16x32_bf16(ap, vf[nb],
                                                                   o[g][nb], 0, 0, 0);
            lac[g] = __builtin_amdgcn_mfma_f32_16x16x32_bf16(ap, ones, lac[g], 0, 0, 0);
            __builtin_amdgcn_s_setprio(0);
        }
    }

#pragma unroll
    for (int g = 0; g < 2; g++)
#pragma unroll
        for (int r = 0; r < 4; r++) {
            const float inv = 1.0f / lac[g][r];
            const int qi = q0 + g * 16 + quad * 4 + r;
#pragma unroll
            for (int nb = 0; nb < 4; nb++)
                oz[(size_t)qi * 1024 + h * 64 + nb * 16 + li] = f2b(o[g][nb][r] * inv);
        }
}

// ---------------------------------------------------------------------------
// ROUND 14: attn_flash4 — 4 INDEPENDENT waves per block, ZERO block barriers,
// per-wave-private LDS. Occupancy lever retried in its clean form: round 1
// failed with barrier-coupled waves + shared Ps; round 6 with separate
// dispatch slots + partial traffic. Here block = 4 consecutive slots of the
// old 2048-slot space (id = blockIdx.x*4 + w); each wave runs the verified
// round-0 body verbatim on its own tab/bias/Ps slice. Wave-private LDS
// roundtrip without barriers is the already-verified Ps pattern. LDS 38.9 KB
// -> 4 blocks/CU = 16 waves/CU offered (vs ~8 resident before). If occupancy
// stays ~21%, the per-CU pin is structural -> revert & converge.
// ---------------------------------------------------------------------------
__global__ __launch_bounds__(256) void attn_flash4(
    const bf16* __restrict__ qb, const bf16* __restrict__ kv0,
    const bf16* __restrict__ kv1,
    const void* __restrict__ rel_emb, bf16* __restrict__ out,
    long qo_bs, long out_bs, int m, int rel_off, const int* __restrict__ flagp) {

    const float SC = 0.125f * 1.44269504f;
    const bool isb = (*flagp != 0);
    const int t256 = threadIdx.x;
    const int w = t256 >> 6;                  // wave id 0..3
    const int t = t256 & 63;                  // lane
    const int id = (int)blockIdx.x * 4 + w;   // 0..2047: old slot space
    const int xcd = id & 7;
    const int slot = id >> 3;
    const int c = (slot >> 6) * 8 + xcd;
    const int h = c & 15, z = c >> 4;
    const int q0 = (slot & 63) * 32;
    const int li = t & 15, quad = t >> 4;

    const bf16* qz = qb + (size_t)z * qo_bs;
    bf16* oz = out + (size_t)z * out_bs;
    const bf16* kb = z ? kv1 : kv0;
    const bf16* vtb = kb + (size_t)m * 1024;

    // Per-wave private LDS slices (no block barriers anywhere).
    __shared__ float tabS[4][2080];           // 33280 B
    __shared__ float biasS[4][32];            //   512 B
    __shared__ bf16  PsS[4][16][40];          //  5120 B
    float* tab = tabS[w];
    float* bias_s = biasS[w];
    bf16 (*Ps)[40] = PsS[w];

    if (t < 32) bias_s[t] = ldx(rel_emb, t * 16 + h, isb) * SC - 40.0f;
    // wave-internal LDS RAW: compiler-inserted lgkmcnt (verified Ps pattern)

    const int tsz = m + 31;
    for (int i = t; i < tsz; i += 64) {
        const int rel = i - 31 - q0 + rel_off;
        const int ab = rel < 0 ? -rel : rel;
        int bucket = rel >= 0 ? 16 : 0;
        if (ab < 8) {
            bucket += ab;
        } else {
            const int p = 31 - __clz(ab);
            const int k2 = 2 * p + ((ab * ab >= (1 << (2 * p + 1))) ? 1 : 0);
            const int val = k2 + 2;
            bucket += (val > 15) ? 15 : val;
        }
        tab[i] = bias_s[bucket];
    }

    bf16x8 aq[2][2];
#pragma unroll
    for (int g = 0; g < 2; g++)
#pragma unroll
        for (int kc = 0; kc < 2; kc++)
            aq[g][kc] = *(const bf16x8*)(qz + (size_t)(q0 + g * 16 + li) * 1024
                                         + h * 64 + kc * 32 + quad * 8);

    bf16x8 ones;
#pragma unroll
    for (int j = 0; j < 8; j++) ((short*)&ones)[j] = 0x3F80;

    f32x4 o[2][4], lac[2];
#pragma unroll
    for (int g = 0; g < 2; g++) {
#pragma unroll
        for (int r = 0; r < 4; r++) lac[g][r] = 0.f;
#pragma unroll
        for (int nb = 0; nb < 4; nb++)
#pragma unroll
            for (int r = 0; r < 4; r++) o[g][nb][r] = 0.f;
    }

    for (int j0 = 0; j0 < m; j0 += 32) {
        bf16x8 kf[4], vf[4];
#pragma unroll
        for (int nb = 0; nb < 2; nb++)
#pragma unroll
            for (int kc = 0; kc < 2; kc++)
                kf[nb * 2 + kc] = *(const bf16x8*)(
                    kb + (size_t)(j0 + nb * 16 + li) * 1024 + h * 64 + kc * 32 + quad * 8);
#pragma unroll
        for (int nb = 0; nb < 4; nb++)
            vf[nb] = *(const bf16x8*)(
                vtb + (size_t)(h * 64 + nb * 16 + li) * m + j0 + quad * 8);

#pragma unroll
        for (int g = 0; g < 2; g++) {
            f32x4 s[2];
            __builtin_amdgcn_s_setprio(1);
#pragma unroll
            for (int nb = 0; nb < 2; nb++) {
                f32x4 a;
#pragma unroll
                for (int r = 0; r < 4; r++) a[r] = 0.f;
#pragma unroll
                for (int kc = 0; kc < 2; kc++)
                    a = __builtin_amdgcn_mfma_f32_16x16x32_bf16(aq[g][kc], kf[nb * 2 + kc],
                                                                a, 0, 0, 0);
                s[nb] = a;
            }
            __builtin_amdgcn_s_setprio(0);
#pragma unroll
            for (int nb = 0; nb < 2; nb++)
#pragma unroll
                for (int r = 0; r < 4; r++) {
                    const int ti = j0 + nb * 16 + li + 31 - (g * 16 + quad * 4 + r);
                    s[nb][r] = exp2f(fmaf(s[nb][r], SC, tab[ti]));
                }
#pragma unroll
            for (int nb = 0; nb < 2; nb++)
#pragma unroll
                for (int r = 0; r < 4; r++)
                    Ps[quad * 4 + r][nb * 16 + li] = f2b(s[nb][r]);
            const bf16x8 ap = *(const bf16x8*)&Ps[li][quad * 8];
            __builtin_amdgcn_s_setprio(1);
#pragma unroll
            for (int nb = 0; nb < 4; nb++)
                o[g][nb] = __builtin_amdgcn_mfma_f32_16x16x32_bf16(ap, vf[nb],
                                                                   o[g][nb], 0, 0, 0);
            lac[g] = __builtin_amdgcn_mfma_f32_16x16x32_bf16(ap, ones, lac[g], 0, 0, 0);
            __builtin_amdgcn_s_setprio(0);
        }
    }

#pragma unroll
    for (int g = 0; g < 2; g++)
#pragma unroll
        for (int r = 0; r < 4; r++) {
            const float inv = 1.0f / lac[g][r];
            const int qi = q0 + g * 16 + quad * 4 + r;
#pragma unroll
            for (int nb = 0; nb < 4; nb++)
                oz[(size_t)qi * 1024 + h * 64 + nb * 16 + li] = f2b(o[g][nb][r] * inv);
        }
}

// ---------------------------------------------------------------------------
// Launcher. Fast path (ws >= 56 MB + 256; measured ws = 256 MB):
//   F_A|F_B|F_C (24 MB) + WT (8) + F_X (8) + F_Y (6) + WT2 (8) = 54 MB.
// Round-13 schedule (best: 455.6 µs) with attn on attn_flash4 (4 independent
// waves/block, no barriers). Fallback: round-7 plan (24 MB).
// ---------------------------------------------------------------------------
extern "C" void kernel_launch(void* const* d_in, const int* in_sizes, int n_in,
                              void* d_out, int out_size, void* d_ws, size_t ws_size,
                              hipStream_t stream) {
    const long M1 = 1024 * 1024;
    const long M2 = 2 * 1024 * 1024;
    const long M4 = 4 * 1024 * 1024;
    if (ws_size < 24u * 1024 * 1024 + 256) return;

    const void* x      = d_in[0];
    const void* ctx    = d_in[1];
    const void* sa_ng  = d_in[2];
    const void* sa_nb  = d_in[3];
    const void* sa_ncg = d_in[4];
    const void* sa_ncb = d_in[5];
    const void* sa_wq  = d_in[6];
    const void* sa_wkv = d_in[7];
    const void* sa_wo  = d_in[8];
    const void* sa_bo  = d_in[9];
    const void* sa_rel = d_in[10];
    const void* ca_ng  = d_in[11];
    const void* ca_nb  = d_in[12];
    const void* ca_ncg = d_in[13];
    const void* ca_ncb = d_in[14];
    const void* ca_wq  = d_in[15];
    const void* ca_wkv = d_in[16];
    const void* ca_wo  = d_in[17];
    const void* ca_bo  = d_in[18];
    const void* ca_rel = d_in[19];

    int* flag = (int*)d_ws;
    bf16* F_A = (bf16*)((char*)d_ws + 256);
    bf16* F_B = F_A + M4;
    bf16* F_C = F_B + M4;
    bf16* WT  = F_C + M4;                // fast path only (SA weights)
    bf16* F_X = WT + M4;                 // fast path only (xn buffer)
    bf16* F_Y = F_X + M4;                // fast path only (ctx-LN + CA K/V)
    bf16* WT2 = F_Y + 3 * M1;            // fast path only (CA weights)
    bf16* qd  = (bf16*)d_out;            // d_out as bf16 scratch (q / ao)

    sniff_kernel<<<1, 256, 0, stream>>>(x, flag);

    if (ws_size >= 56u * 1024 * 1024 + 256) {
        bf16* WTq  = WT;                 // [1024][1024]
        bf16* WTkv = WT + M1;            // [2048][1024]
        bf16* WTo  = WT + 3 * M1;        // [1024][1024]
        bf16* WT2q  = WT2;
        bf16* WT2kv = WT2 + M1;
        bf16* WT2o  = WT2 + 3 * M1;
        bf16* CAK0 = F_Y + M1;           // z0: K[512][1024] + V^T[1024][512]
        bf16* CAK1 = F_Y + 2 * M1;       // z1: same layout

        // ===== prologue: weight transposes + both input LNs (ONE dispatch)
        prologue_kernel<<<dim3(7168), 256, 0, stream>>>(
            sa_wq, sa_wkv, sa_wo, ca_wq, ca_wkv, ca_wo,
            WTq, WTkv, WTo, WT2q, WT2kv, WT2o,
            x, ctx, sa_ng, sa_nb, sa_ncg, sa_ncb, ca_ncg, ca_ncb,
            F_X, F_B, F_Y, flag);

        // ===== BIG (128^2): SA-q + SA-kv + CA-kv =====
        {
            GArgs gq = {};
            gq.A = F_X; gq.Bt = WTq; gq.C = qd;
            gq.N = 1024; gq.nbx = 8; gq.nby = 32;
            GArgs gkv = {};
            gkv.A = F_B; gkv.Bt = WTkv;
            gkv.N = 2048; gkv.mode = 1; gkv.zsplit = 2048; gkv.zrows = 2048;
            gkv.kb0 = F_A; gkv.kb1 = F_C; gkv.nbx = 16; gkv.nby = 32;
            GArgs gca = {};
            gca.A = F_Y; gca.Bt = WT2kv;
            gca.N = 2048; gca.mode = 1; gca.zsplit = 512; gca.zrows = 512;
            gca.kb0 = CAK0; gca.kb1 = CAK1; gca.nbx = 16; gca.nby = 8;
            gemm_fused<<<dim3(40, 32), 256, 0, stream>>>(gq, gkv, gca, flag);
        }

        // ===== self-attention + o-proj =====
        attn_flash4<<<dim3(512), 256, 0, stream>>>(
            qd, F_A, F_C, sa_rel, qd, M2, M2, 2048, 0, flag);
        gemm_t64<<<dim3(16, 64), 256, 0, stream>>>(
            qd, WTo, F_B, 0, sa_bo, x, 1, 1024, flag);

        // ===== cross-attention =====
        ln_dual_kernel<<<dim3(2048, 1, 2), 256, 0, stream>>>(
            F_B, 0, M2, 0, ca_ng, ca_nb, nullptr, nullptr, F_X, nullptr, M2, flag);
        gemm_t64<<<dim3(16, 64), 256, 0, stream>>>(
            F_X, WT2q, qd, 0, nullptr, nullptr, 0, 1024, flag);
        attn_flash4<<<dim3(512), 256, 0, stream>>>(
            qd, CAK0, CAK1, ca_rel, F_C, M2, M2, 512, 1536, flag);
        gemm_t64<<<dim3(16, 64), 256, 0, stream>>>(
            F_C, WT2o, d_out, 1, ca_bo, F_B, 0, 1024, flag);
        return;
    }

    // ================= fallback: round-7 verified plan =================
    ln_dual_kernel<<<dim3(2048, 1, 2), 256, 0, stream>>>(
        x, 0, M2, 1, sa_ng, sa_nb, sa_ncg, sa_ncb, F_A, F_B, M2, flag);
    gemm_mfma<<<dim3(16, 32, 2), 256, 0, stream>>>(
        F_A, M2, sa_wq, qd, 0, M2, 0, nullptr, nullptr, 0, 0, 0,
        1024, 1024, 0, 0, nullptr, nullptr, flag);
    gemm_mfma<<<dim3(32, 32, 2), 256, 0, stream>>>(
        F_B, M2, sa_wkv, nullptr, 0, 0, 0, nullptr, nullptr, 0, 0, 0,
        1024, 2048, 1, 2048, F_A, F_C, flag);
    attn_flash<<<dim3(2048), 64, 0, stream>>>(
        qd, F_A, F_C, sa_rel, qd, M2, M2, 2048, 0, flag);
    gemm_mfma<<<dim3(16, 32, 2), 256, 0, stream>>>(
        qd, M2, sa_wo, F_B, 0, M2, 0, sa_bo, x, 0, M2, 1,
        1024, 1024, 0, 0, nullptr, nullptr, flag);

    ln_dual_kernel<<<dim3(2048, 1, 2), 256, 0, stream>>>(
        F_B, 0, M2, 0, ca_ng, ca_nb, nullptr, nullptr, F_A, nullptr, M2, flag);
    ln_dual_kernel<<<dim3(512, 1, 2), 256, 0, stream>>>(
        ctx, 0, 512 * 1024, 1, ca_ncg, ca_ncb, nullptr, nullptr,
        F_C, nullptr, 512 * 1024, flag);
    gemm_mfma<<<dim3(16, 32, 2), 256, 0, stream>>>(
        F_A, M2, ca_wq, qd, 0, M2, 0, nullptr, nullptr, 0, 0, 0,
        1024, 1024, 0, 0, nullptr, nullptr, flag);
    gemm_mfma<<<dim3(32, 8, 2), 256, 0, stream>>>(
        F_C, 512 * 1024, ca_wkv, nullptr, 0, 0, 0, nullptr, nullptr, 0, 0, 0,
        1024, 2048, 1, 512, F_A, F_A + M1, flag);
    attn_flash<<<dim3(2048), 64, 0, stream>>>(
        qd, F_A, F_A + M1, ca_rel, F_C, M2, M2, 512, 1536, flag);
    gemm_mfma<<<dim3(16, 32, 2), 256, 0, stream>>>(
        F_C, M2, ca_wo, d_out, 0, M2, 1, ca_bo, F_B, 0, M2, 0,
        1024, 1024, 0, 0, nullptr, nullptr, flag);
}